// Round 3
// baseline (1887.920 us; speedup 1.0000x reference)
//
#include <hip/hip_runtime.h>
#include <hip/hip_bf16.h>
#include <math.h>

typedef __hip_bfloat16 bf16;

#define N_NODE 4096
#define DIM 200
#define NH 8
#define SEQ 4

__device__ __forceinline__ float eluf(float x) { return x > 0.f ? x : expm1f(x); }
__device__ __forceinline__ float sigm(float x) { return 1.f / (1.f + expf(-x)); }

// typed load/store for buffers whose dtype is runtime-detected
template<bool ISB>
__device__ __forceinline__ float ldv(const void* p, size_t i) {
    if (ISB) return __bfloat162float(((const bf16*)p)[i]);
    else     return ((const float*)p)[i];
}
template<bool ISB>
__device__ __forceinline__ void stv(void* p, size_t i, float v) {
    if (ISB) ((bf16*)p)[i] = __float2bfloat16(v);
    else     ((float*)p)[i] = v;
}

// Detect input dtype from feats (values ~ N(0,1)).
// bf16 buffer: even-position uint16s are bf16 samples -> exponent in [100,140] almost surely.
// f32 buffer: even-position uint16s are low mantissa halves -> random -> ~16% plausible.
__global__ void k_detect(const void* feats, int* flag) {
    __shared__ int cnt;
    if (threadIdx.x == 0) cnt = 0;
    __syncthreads();
    const unsigned short* u = (const unsigned short*)feats;
    unsigned short v = u[2 * threadIdx.x];
    int e = (v >> 7) & 0xFF;
    if (e >= 100 && e <= 140) atomicAdd(&cnt, 1);
    __syncthreads();
    if (threadIdx.x == 0) *flag = (cnt >= 128) ? 1 : 0;
}

// ---------------- GAT branch ----------------

// W2s[o][i] = sum over 8 heads of W2[o][head*200 + i]
template<bool ISB>
__device__ void w2sum_body(const void* W2, float* W2s) {
    int idx = blockIdx.x * 256 + threadIdx.x;
    if (idx >= DIM * DIM) return;
    int o = idx / DIM, i = idx % DIM;
    float s = 0.f;
    for (int k = 0; k < NH; k++) s += ldv<ISB>(W2, (size_t)o * (NH * DIM) + k * DIM + i);
    W2s[idx] = s;
}
__global__ void k_w2sum(const int* fl, const void* W2, float* W2s) {
    if (*fl) w2sum_body<true>(W2, W2s); else w2sum_body<false>(W2, W2s);
}

// H[r][o] = elu( sum_k X[r][k] * W1[o][k] + b1[o] )
template<bool ISB>
__device__ void gat1_body(const void* X, const void* W, const void* b, float* H, int M) {
    int idx = blockIdx.x * 256 + threadIdx.x;
    if (idx >= M * DIM) return;
    int r = idx / DIM, o = idx % DIM;
    size_t xb = (size_t)r * DIM, wb = (size_t)o * DIM;
    float acc = ldv<ISB>(b, o);
#pragma unroll 4
    for (int k = 0; k < DIM; k++) acc += ldv<ISB>(X, xb + k) * ldv<ISB>(W, wb + k);
    H[idx] = eluf(acc);
}
__global__ void k_gat1(const int* fl, const void* X, const void* W, const void* b,
                       float* H, int M) {
    if (*fl) gat1_body<true>(X, W, b, H, M); else gat1_body<false>(X, W, b, H, M);
}

// O[r][o] = elu( sum_k H[r][k] * W2s[o][k] + b2[o] )
template<bool ISB>
__device__ void gat2_body(const float* H, const float* W2s, const void* b2,
                          float* O, int M) {
    int idx = blockIdx.x * 256 + threadIdx.x;
    if (idx >= M * DIM) return;
    int r = idx / DIM, o = idx % DIM;
    const float* x = H + (size_t)r * DIM;
    const float* w = W2s + (size_t)o * DIM;
    float acc = ldv<ISB>(b2, o);
#pragma unroll 4
    for (int k = 0; k < DIM; k++) acc += x[k] * w[k];
    O[idx] = eluf(acc);
}
__global__ void k_gat2(const int* fl, const float* H, const float* W2s, const void* b2,
                       float* O, int M) {
    if (*fl) gat2_body<true>(H, W2s, b2, O, M); else gat2_body<false>(H, W2s, b2, O, M);
}

// embeds[t][i][j] = softmax_j( O_t_flat[j*4096 + i] ); one 64-thread block per (t,i)
template<bool ISB>
__device__ void softmax_body(const float* O, void* out) {
    int t = blockIdx.x >> 12;
    int i = blockIdx.x & (N_NODE - 1);
    const float* ob = O + (size_t)t * N_NODE * DIM;
    int lane = threadIdx.x;
    int j0 = lane, j1 = lane + 64, j2 = lane + 128, j3 = lane + 192;
    bool h3 = (j3 < DIM);
    float v0 = ob[(size_t)j0 * N_NODE + i];
    float v1 = ob[(size_t)j1 * N_NODE + i];
    float v2 = ob[(size_t)j2 * N_NODE + i];
    float v3 = h3 ? ob[(size_t)j3 * N_NODE + i] : -1e30f;
    float m = fmaxf(fmaxf(v0, v1), fmaxf(v2, v3));
    for (int off = 32; off > 0; off >>= 1) m = fmaxf(m, __shfl_xor(m, off));
    float e0 = expf(v0 - m), e1 = expf(v1 - m), e2 = expf(v2 - m);
    float e3 = h3 ? expf(v3 - m) : 0.f;
    float s = e0 + e1 + e2 + e3;
    for (int off = 32; off > 0; off >>= 1) s += __shfl_xor(s, off);
    float inv = 1.f / s;
    size_t base = ((size_t)t * N_NODE + i) * DIM;
    stv<ISB>(out, base + j0, e0 * inv);
    stv<ISB>(out, base + j1, e1 * inv);
    stv<ISB>(out, base + j2, e2 * inv);
    if (h3) stv<ISB>(out, base + j3, e3 * inv);
}
__global__ void k_softmax(const int* fl, const float* O, void* out) {
    if (*fl) softmax_body<true>(O, out); else softmax_body<false>(O, out);
}

// ---------------- GRU branch ----------------

template<bool ISB>
__device__ void wvinit_body(const void* iwv, float* wv) {
    int idx = blockIdx.x * 256 + threadIdx.x;
    if (idx < NH * DIM * DIM) wv[idx] = ldv<ISB>(iwv, idx);
}
__global__ void k_wvinit(const int* fl, const void* iwv, float* wv) {
    if (*fl) wvinit_body<true>(iwv, wv); else wvinit_body<false>(iwv, wv);
}

// Sparse AW[s][g][i][col] = sum_k adj[s+1][i][k] * Wg[k][col].
// One block per (row i, step s); per-row nonzero compaction into LDS.
template<bool ISB>
__device__ void aw_body(const void* adjs, const void* Wr, const void* Wu,
                        const void* Wh, float* AW) {
    int i = blockIdx.x;
    int s = blockIdx.y;
    size_t arow = ((size_t)(s + 1) * N_NODE + i) * N_NODE;
    __shared__ int   s_k[256];
    __shared__ float s_v[256];
    __shared__ int   s_cnt;
    int tid = threadIdx.x;
    int c0 = tid, c1 = tid + 256, c2 = tid + 512;
    int g0 = c0 / DIM, o0 = c0 % DIM;          // g0 in {0,1}
    int g1 = c1 / DIM, o1 = c1 % DIM;          // g1 in {1,2}
    bool has2 = (c2 < 600);
    int g2 = 2, o2 = has2 ? (c2 % DIM) : 0;
    const void* w0 = (g0 == 0) ? Wr : Wu;
    const void* w1 = (g1 == 1) ? Wu : Wh;
    const void* w2 = Wh;
    float a0 = 0.f, a1 = 0.f, a2 = 0.f;
    for (int base = 0; base < N_NODE; base += 256) {
        if (tid == 0) s_cnt = 0;
        __syncthreads();
        float av = ldv<ISB>(adjs, arow + base + tid);
        if (av != 0.f) {
            int p = atomicAdd(&s_cnt, 1);
            s_k[p] = base + tid; s_v[p] = av;
        }
        __syncthreads();
        int n = s_cnt;
        for (int e = 0; e < n; e++) {
            int k = s_k[e]; float v = s_v[e];
            a0 += v * ldv<ISB>(w0, (size_t)k * DIM + o0);
            a1 += v * ldv<ISB>(w1, (size_t)k * DIM + o1);
            if (has2) a2 += v * ldv<ISB>(w2, (size_t)k * DIM + o2);
        }
        __syncthreads();
    }
    size_t sg = (size_t)s * 3;
    AW[((sg + g0) * N_NODE + i) * DIM + o0] = a0;
    AW[((sg + g1) * N_NODE + i) * DIM + o1] = a1;
    if (has2) AW[((sg + g2) * N_NODE + i) * DIM + o2] = a2;
}
__global__ void k_aw(const int* fl, const void* adjs, const void* Wr,
                     const void* Wu, const void* Wh, float* AW) {
    if (*fl) aw_body<true>(adjs, Wr, Wu, Wh, AW);
    else     aw_body<false>(adjs, Wr, Wu, Wh, AW);
}

// G[sg][a][b] = sum_k Pg[a][k] * AW[sg][k][b] + bg[a][b]; tiled over K=4096
template<bool ISB>
__device__ void pg_body(const void* Pr, const void* Pu, const void* Ph,
                        const void* br, const void* bu, const void* bh,
                        const float* AW, float* G) {
    int sg = blockIdx.z;
    int g = sg % 3;
    const void* P  = (g == 0) ? Pr : (g == 1) ? Pu : Ph;
    const void* bb = (g == 0) ? br : (g == 1) ? bu : bh;
    const float* A = AW + (size_t)sg * N_NODE * DIM;
    int ty = threadIdx.y, tx = threadIdx.x;
    int a = blockIdx.y * 16 + ty, b = blockIdx.x * 16 + tx;
    __shared__ float Pt[16][17];
    __shared__ float At[16][17];
    float acc = 0.f;
    for (int k0 = 0; k0 < N_NODE; k0 += 16) {
        Pt[ty][tx] = (a < DIM) ? ldv<ISB>(P, (size_t)a * N_NODE + k0 + tx) : 0.f;
        At[ty][tx] = (b < DIM) ? A[(size_t)(k0 + ty) * DIM + b] : 0.f;
        __syncthreads();
#pragma unroll
        for (int kk = 0; kk < 16; kk++) acc += Pt[ty][kk] * At[kk][tx];
        __syncthreads();
    }
    if (a < DIM && b < DIM)
        G[(size_t)sg * DIM * DIM + a * DIM + b] = acc + ldv<ISB>(bb, a * DIM + b);
}
__global__ void k_pg(const int* fl, const void* Pr, const void* Pu, const void* Ph,
                     const void* br, const void* bu, const void* bh,
                     const float* AW, float* G) {
    if (*fl) pg_body<true>(Pr, Pu, Ph, br, bu, bh, AW, G);
    else     pg_body<false>(Pr, Pu, Ph, br, bu, bh, AW, G);
}

// r = sigm(Gr + wv@Ur); u = sigm(Gu + wv@Uu); rw = r*wv
template<bool ISB>
__device__ void ru_body(const float* wv, const void* Ur, const void* Uu,
                        const float* Gr, const float* Gu, float* u, float* rw) {
    int idx = blockIdx.x * 256 + threadIdx.x;
    if (idx >= NH * DIM * DIM) return;
    int h = idx / (DIM * DIM);
    int rem = idx % (DIM * DIM);
    int a = rem / DIM, b = rem % DIM;
    const float* row = wv + (size_t)h * DIM * DIM + (size_t)a * DIM;
    float ar = 0.f, au = 0.f;
#pragma unroll 4
    for (int k = 0; k < DIM; k++) {
        float w = row[k];
        ar += w * ldv<ISB>(Ur, (size_t)k * DIM + b);
        au += w * ldv<ISB>(Uu, (size_t)k * DIM + b);
    }
    float rv = sigm(Gr[rem] + ar);
    u[idx]  = sigm(Gu[rem] + au);
    rw[idx] = rv * row[b];
}
__global__ void k_ru(const int* fl, const float* wv, const void* Ur, const void* Uu,
                     const float* Gr, const float* Gu, float* u, float* rw) {
    if (*fl) ru_body<true>(wv, Ur, Uu, Gr, Gu, u, rw);
    else     ru_body<false>(wv, Ur, Uu, Gr, Gu, u, rw);
}

// hcap = tanh(Gh + rw@Uh); wv = (1-u)*wv + u*hcap
template<bool ISB>
__device__ void hstep_body(float* wv, const float* rw, const void* Uh,
                           const float* Gh, const float* u) {
    int idx = blockIdx.x * 256 + threadIdx.x;
    if (idx >= NH * DIM * DIM) return;
    int h = idx / (DIM * DIM);
    int rem = idx % (DIM * DIM);
    int a = rem / DIM, b = rem % DIM;
    const float* row = rw + (size_t)h * DIM * DIM + (size_t)a * DIM;
    float acc = 0.f;
#pragma unroll 4
    for (int k = 0; k < DIM; k++) acc += row[k] * ldv<ISB>(Uh, (size_t)k * DIM + b);
    float hc = tanhf(Gh[rem] + acc);
    float uu = u[idx];
    wv[idx] = (1.f - uu) * wv[idx] + uu * hc;
}
__global__ void k_hstep(const int* fl, float* wv, const float* rw, const void* Uh,
                        const float* Gh, const float* u) {
    if (*fl) hstep_body<true>(wv, rw, Uh, Gh, u);
    else     hstep_body<false>(wv, rw, Uh, Gh, u);
}

// final_wv -> out at element offset SEQ*N_NODE*DIM (elements of the detected dtype)
template<bool ISB>
__device__ void wvout_body(const float* wv, void* out) {
    int idx = blockIdx.x * 256 + threadIdx.x;
    if (idx < NH * DIM * DIM)
        stv<ISB>(out, (size_t)SEQ * N_NODE * DIM + idx, wv[idx]);
}
__global__ void k_wvout(const int* fl, const float* wv, void* out) {
    if (*fl) wvout_body<true>(wv, out); else wvout_body<false>(wv, out);
}

extern "C" void kernel_launch(void* const* d_in, const int* in_sizes, int n_in,
                              void* d_out, int out_size, void* d_ws, size_t ws_size,
                              hipStream_t stream) {
    const void* adjs    = d_in[0];
    const void* feats   = d_in[1];
    const void* init_wv = d_in[3];
    const void* W1 = d_in[4];
    const void* b1 = d_in[5];
    const void* W2 = d_in[10];
    const void* b2 = d_in[11];
    const void* Wr = d_in[16];
    const void* Ur = d_in[17];
    const void* Pr = d_in[18];
    const void* br = d_in[19];
    const void* Wu = d_in[20];
    const void* Uu = d_in[21];
    const void* Pu = d_in[22];
    const void* bu = d_in[23];
    const void* Wh = d_in[24];
    const void* Uh = d_in[25];
    const void* Ph = d_in[26];
    const void* bh = d_in[27];

    // workspace layout (floats); flag occupies the first 64 floats' worth.
    int*   flag = (int*)d_ws;
    float* ws   = (float*)d_ws + 64;
    float* W2s  = ws;                                   // 40000
    float* big  = ws + 40000;                           // max(2*3276800, 9*819200)=7372800
    float* Hbuf = big;
    float* Obuf = big + (size_t)SEQ * N_NODE * DIM;     // 3276800
    float* AW   = big;                                  // aliases Hbuf/Obuf (dead by then)
    float* G    = big + 7372800;                        // 9*40000 = 360000
    float* wv   = G + 360000;                           // 320000
    float* ubuf = wv + 320000;                          // 320000
    float* rwbuf= ubuf + 320000;                        // 320000
    // total ~8.73M floats ~= 35 MB

    const int M = SEQ * N_NODE;               // 16384
    const int WVN = NH * DIM * DIM;           // 320000

    k_detect<<<1, 256, 0, stream>>>(feats, flag);

    // ---- GAT branch ----
    k_w2sum<<<(DIM * DIM + 255) / 256, 256, 0, stream>>>(flag, W2, W2s);
    k_gat1<<<(M * DIM + 255) / 256, 256, 0, stream>>>(flag, feats, W1, b1, Hbuf, M);
    k_gat2<<<(M * DIM + 255) / 256, 256, 0, stream>>>(flag, Hbuf, W2s, b2, Obuf, M);
    k_softmax<<<SEQ * N_NODE, 64, 0, stream>>>(flag, Obuf, d_out);

    // ---- GRU branch ----
    k_wvinit<<<(WVN + 255) / 256, 256, 0, stream>>>(flag, init_wv, wv);
    {
        dim3 g(N_NODE, 3);
        k_aw<<<g, 256, 0, stream>>>(flag, adjs, Wr, Wu, Wh, AW);
    }
    {
        dim3 g(13, 13, 9);
        dim3 b(16, 16);
        k_pg<<<g, b, 0, stream>>>(flag, Pr, Pu, Ph, br, bu, bh, AW, G);
    }
    for (int s = 0; s < 3; s++) {
        const float* Gr = G + (size_t)(s * 3 + 0) * DIM * DIM;
        const float* Gu = G + (size_t)(s * 3 + 1) * DIM * DIM;
        const float* Gh = G + (size_t)(s * 3 + 2) * DIM * DIM;
        k_ru<<<(WVN + 255) / 256, 256, 0, stream>>>(flag, wv, Ur, Uu, Gr, Gu, ubuf, rwbuf);
        k_hstep<<<(WVN + 255) / 256, 256, 0, stream>>>(flag, wv, rwbuf, Uh, Gh, ubuf);
    }
    k_wvout<<<(WVN + 255) / 256, 256, 0, stream>>>(flag, wv, d_out);
}

// Round 4
// 1222.363 us; speedup vs baseline: 1.5445x; 1.5445x over previous
//
#include <hip/hip_runtime.h>
#include <hip/hip_bf16.h>
#include <math.h>

typedef __hip_bfloat16 bf16;

#define N_NODE 4096
#define DIM 200
#define NH 8
#define SEQ 4

__device__ __forceinline__ float eluf(float x) { return x > 0.f ? x : expm1f(x); }
__device__ __forceinline__ float sigm(float x) { return 1.f / (1.f + expf(-x)); }

template<bool ISB>
__device__ __forceinline__ float ldv(const void* p, size_t i) {
    if (ISB) return __bfloat162float(((const bf16*)p)[i]);
    else     return ((const float*)p)[i];
}
template<bool ISB>
__device__ __forceinline__ void stv(void* p, size_t i, float v) {
    if (ISB) ((bf16*)p)[i] = __float2bfloat16(v);
    else     ((float*)p)[i] = v;
}

// Detect input dtype from feats (values ~ N(0,1)). See round-1/2 analysis.
__global__ void k_detect(const void* feats, int* flag) {
    __shared__ int cnt;
    if (threadIdx.x == 0) cnt = 0;
    __syncthreads();
    const unsigned short* u = (const unsigned short*)feats;
    unsigned short v = u[2 * threadIdx.x];
    int e = (v >> 7) & 0xFF;
    if (e >= 100 && e <= 140) atomicAdd(&cnt, 1);
    __syncthreads();
    if (threadIdx.x == 0) *flag = (cnt >= 128) ? 1 : 0;
}

// ---------------- tiled GEMM core ----------------
// C-tile 64x64 per block, 256 threads, 4x4 micro-tile/thread, K-chunk 8.
// A: [M x lda] (runtime dtype via AISB), B: [K x 200] f32 row-major.
// N fixed at 200. Epilogues:
//  0: C[row*200+col] = elu(acc + X1[col])                      (GAT linears)
//  1: C = sigm(X1[(row%200)*200+col] + acc) * X2[row*200+col]  (r-gate -> rw)
//  2: C = sigm(X1[(row%200)*200+col] + acc)                    (u-gate)
//  3: wv update: C = (1-u)*C + u*tanh(X1[(row%200)*200+col]+acc), u=X2
//  4: C = acc + X1[row*200+col]                                (P@AW + bias)
template<int EPI, bool AISB>
__device__ void gemm_body(const void* A, int lda, const float* B, int M, int K,
                          const float* X1, const float* X2, float* C,
                          int row0, int c0) {
    const int N = DIM;
    int tid = threadIdx.x;
    int tx = tid & 15, ty = tid >> 4;
    __shared__ float As[8][64];
    __shared__ float Bs[8][64];
    float acc[4][4] = {};
    int ar = tid >> 2;            // 0..63 (A tile row)
    int ak = (tid & 3) * 2;       // 0,2,4,6 (A tile k)
    int bk = tid >> 5;            // 0..7  (B tile k)
    int bc = (tid & 31) * 2;      // 0..62 (B tile col)
    for (int k0 = 0; k0 < K; k0 += 8) {
        float a0 = 0.f, a1 = 0.f;
        if (row0 + ar < M) {
            size_t base = (size_t)(row0 + ar) * lda + k0 + ak;
            a0 = ldv<AISB>(A, base);
            a1 = ldv<AISB>(A, base + 1);
        }
        float b0 = (c0 + bc     < N) ? B[(size_t)(k0 + bk) * N + c0 + bc]     : 0.f;
        float b1 = (c0 + bc + 1 < N) ? B[(size_t)(k0 + bk) * N + c0 + bc + 1] : 0.f;
        __syncthreads();
        As[ak][ar] = a0; As[ak + 1][ar] = a1;
        Bs[bk][bc] = b0; Bs[bk][bc + 1]  = b1;
        __syncthreads();
#pragma unroll
        for (int kk = 0; kk < 8; kk++) {
            float av[4], bv[4];
            *(float4*)av = *(const float4*)&As[kk][ty * 4];
            *(float4*)bv = *(const float4*)&Bs[kk][tx * 4];
#pragma unroll
            for (int i = 0; i < 4; i++)
#pragma unroll
                for (int j = 0; j < 4; j++) acc[i][j] += av[i] * bv[j];
        }
    }
#pragma unroll
    for (int i = 0; i < 4; i++) {
        int row = row0 + ty * 4 + i;
        if (row >= M) continue;
        int a200 = row - (row / 200) * 200;
#pragma unroll
        for (int j = 0; j < 4; j++) {
            int col = c0 + tx * 4 + j;
            if (col >= N) continue;
            float v = acc[i][j];
            size_t ci = (size_t)row * 200 + col;
            if (EPI == 0) {
                C[ci] = eluf(v + X1[col]);
            } else if (EPI == 1) {
                C[ci] = sigm(X1[a200 * 200 + col] + v) * X2[ci];
            } else if (EPI == 2) {
                C[ci] = sigm(X1[a200 * 200 + col] + v);
            } else if (EPI == 3) {
                float uu = X2[ci];
                float hc = tanhf(X1[a200 * 200 + col] + v);
                C[ci] = (1.f - uu) * C[ci] + uu * hc;
            } else {
                C[ci] = v + X1[ci];
            }
        }
    }
}

// EPI 0 with runtime-dtype A (gat1) or f32 A (gat2)
__global__ __launch_bounds__(256) void k_gemm_e0(const int* fl, int useIsb,
        const void* A, int lda, const float* B, int M, int K,
        const float* bias, float* C) {
    int row0 = blockIdx.y * 64, c0 = blockIdx.x * 64;
    if (useIsb && *fl) gemm_body<0, true >(A, lda, B, M, K, bias, nullptr, C, row0, c0);
    else               gemm_body<0, false>(A, lda, B, M, K, bias, nullptr, C, row0, c0);
}
__global__ __launch_bounds__(256) void k_gemm_e1(const float* A, const float* B,
        const float* G0, const float* WV, float* C) {
    gemm_body<1, false>(A, DIM, B, NH * DIM, DIM, G0, WV, C, blockIdx.y * 64, blockIdx.x * 64);
}
__global__ __launch_bounds__(256) void k_gemm_e2(const float* A, const float* B,
        const float* G0, float* C) {
    gemm_body<2, false>(A, DIM, B, NH * DIM, DIM, G0, nullptr, C, blockIdx.y * 64, blockIdx.x * 64);
}
__global__ __launch_bounds__(256) void k_gemm_e3(const float* A, const float* B,
        const float* G0, const float* U, float* WV) {
    gemm_body<3, false>(A, DIM, B, NH * DIM, DIM, G0, U, WV, blockIdx.y * 64, blockIdx.x * 64);
}
// P@AW for all 9 (step,gate) pairs in one launch; z = sg = s*3+g
__global__ __launch_bounds__(256) void k_pggemm(const int* fl,
        const void* P0, const void* P1, const void* P2,
        const float* AW, const float* bgf, float* G) {
    int sg = blockIdx.z;
    int g = sg - (sg / 3) * 3;
    const void* A = (g == 0) ? P0 : (g == 1) ? P1 : P2;
    const float* B = AW + (size_t)sg * N_NODE * DIM;
    const float* bias2d = bgf + (size_t)g * DIM * DIM;
    float* C = G + (size_t)sg * DIM * DIM;
    int row0 = blockIdx.y * 64, c0 = blockIdx.x * 64;
    if (*fl) gemm_body<4, true >(A, N_NODE, B, DIM, N_NODE, bias2d, nullptr, C, row0, c0);
    else     gemm_body<4, false>(A, N_NODE, B, DIM, N_NODE, bias2d, nullptr, C, row0, c0);
}

// ---------------- prep kernels ----------------

// W1t[k][n] = W1[n][k]; W2t[k][n] = sum_h W2[n][h*200+k]; b1f/b2f f32 copies
template<bool ISB>
__device__ void prepw_body(const void* W1, const void* b1, const void* W2,
                           const void* b2, float* W1t, float* W2t,
                           float* b1f, float* b2f) {
    int idx = blockIdx.x * 256 + threadIdx.x;
    if (idx < 40000) {
        int k = idx / 200, n = idx % 200;
        W1t[idx] = ldv<ISB>(W1, (size_t)n * 200 + k);
    } else if (idx < 80000) {
        int r = idx - 40000;
        int k = r / 200, n = r % 200;
        float s = 0.f;
        for (int h = 0; h < NH; h++) s += ldv<ISB>(W2, (size_t)n * 1600 + h * 200 + k);
        W2t[r] = s;
    } else if (idx < 80256) {
        int j = idx - 80000;
        b1f[j] = (j < 200) ? ldv<ISB>(b1, j) : 0.f;
    } else if (idx < 80512) {
        int j = idx - 80256;
        b2f[j] = (j < 200) ? ldv<ISB>(b2, j) : 0.f;
    }
}
__global__ void k_prepw(const int* fl, const void* W1, const void* b1,
                        const void* W2, const void* b2, float* W1t, float* W2t,
                        float* b1f, float* b2f) {
    if (*fl) prepw_body<true >(W1, b1, W2, b2, W1t, W2t, b1f, b2f);
    else     prepw_body<false>(W1, b1, W2, b2, W1t, W2t, b1f, b2f);
}

// Utf[g] = f32(U_g) (already [k][n]); bgf[g] = f32(b_g); wv = f32(init_wv)
template<bool ISB>
__device__ void prepu_body(const void* Ur, const void* Uu, const void* Uh,
                           const void* br, const void* bu, const void* bh,
                           const void* iwv, float* Utf, float* bgf, float* wv) {
    int idx = blockIdx.x * 256 + threadIdx.x;
    if (idx < 120000) {
        int g = idx / 40000, r = idx - g * 40000;
        const void* U = (g == 0) ? Ur : (g == 1) ? Uu : Uh;
        Utf[idx] = ldv<ISB>(U, r);
    } else if (idx < 240000) {
        int j = idx - 120000;
        int g = j / 40000, r = j - g * 40000;
        const void* bb = (g == 0) ? br : (g == 1) ? bu : bh;
        bgf[j] = ldv<ISB>(bb, r);
    } else if (idx < 240000 + NH * DIM * DIM) {
        int j = idx - 240000;
        wv[j] = ldv<ISB>(iwv, j);
    }
}
__global__ void k_prepu(const int* fl, const void* Ur, const void* Uu, const void* Uh,
                        const void* br, const void* bu, const void* bh,
                        const void* iwv, float* Utf, float* bgf, float* wv) {
    if (*fl) prepu_body<true >(Ur, Uu, Uh, br, bu, bh, iwv, Utf, bgf, wv);
    else     prepu_body<false>(Ur, Uu, Uh, br, bu, bh, iwv, Utf, bgf, wv);
}

// ---------------- softmax (unchanged, verified) ----------------
template<bool ISB>
__device__ void softmax_body(const float* O, void* out) {
    int t = blockIdx.x >> 12;
    int i = blockIdx.x & (N_NODE - 1);
    const float* ob = O + (size_t)t * N_NODE * DIM;
    int lane = threadIdx.x;
    int j0 = lane, j1 = lane + 64, j2 = lane + 128, j3 = lane + 192;
    bool h3 = (j3 < DIM);
    float v0 = ob[(size_t)j0 * N_NODE + i];
    float v1 = ob[(size_t)j1 * N_NODE + i];
    float v2 = ob[(size_t)j2 * N_NODE + i];
    float v3 = h3 ? ob[(size_t)j3 * N_NODE + i] : -1e30f;
    float m = fmaxf(fmaxf(v0, v1), fmaxf(v2, v3));
    for (int off = 32; off > 0; off >>= 1) m = fmaxf(m, __shfl_xor(m, off));
    float e0 = expf(v0 - m), e1 = expf(v1 - m), e2 = expf(v2 - m);
    float e3 = h3 ? expf(v3 - m) : 0.f;
    float s = e0 + e1 + e2 + e3;
    for (int off = 32; off > 0; off >>= 1) s += __shfl_xor(s, off);
    float inv = 1.f / s;
    size_t base = ((size_t)t * N_NODE + i) * DIM;
    stv<ISB>(out, base + j0, e0 * inv);
    stv<ISB>(out, base + j1, e1 * inv);
    stv<ISB>(out, base + j2, e2 * inv);
    if (h3) stv<ISB>(out, base + j3, e3 * inv);
}
__global__ void k_softmax(const int* fl, const float* O, void* out) {
    if (*fl) softmax_body<true>(O, out); else softmax_body<false>(O, out);
}

// ---------------- sparse A@W (unchanged, verified) ----------------
template<bool ISB>
__device__ void aw_body(const void* adjs, const void* Wr, const void* Wu,
                        const void* Wh, float* AW) {
    int i = blockIdx.x;
    int s = blockIdx.y;
    size_t arow = ((size_t)(s + 1) * N_NODE + i) * N_NODE;
    __shared__ int   s_k[256];
    __shared__ float s_v[256];
    __shared__ int   s_cnt;
    int tid = threadIdx.x;
    int c0 = tid, c1 = tid + 256, c2 = tid + 512;
    int g0 = c0 / DIM, o0 = c0 % DIM;
    int g1 = c1 / DIM, o1 = c1 % DIM;
    bool has2 = (c2 < 600);
    int o2 = has2 ? (c2 % DIM) : 0;
    const void* w0 = (g0 == 0) ? Wr : Wu;
    const void* w1 = (g1 == 1) ? Wu : Wh;
    const void* w2 = Wh;
    float a0 = 0.f, a1 = 0.f, a2 = 0.f;
    for (int base = 0; base < N_NODE; base += 256) {
        if (tid == 0) s_cnt = 0;
        __syncthreads();
        float av = ldv<ISB>(adjs, arow + base + tid);
        if (av != 0.f) {
            int p = atomicAdd(&s_cnt, 1);
            s_k[p] = base + tid; s_v[p] = av;
        }
        __syncthreads();
        int n = s_cnt;
        for (int e = 0; e < n; e++) {
            int k = s_k[e]; float v = s_v[e];
            a0 += v * ldv<ISB>(w0, (size_t)k * DIM + o0);
            a1 += v * ldv<ISB>(w1, (size_t)k * DIM + o1);
            if (has2) a2 += v * ldv<ISB>(w2, (size_t)k * DIM + o2);
        }
        __syncthreads();
    }
    size_t sg = (size_t)s * 3;
    AW[((sg + g0) * N_NODE + i) * DIM + o0] = a0;
    AW[((sg + g1) * N_NODE + i) * DIM + o1] = a1;
    if (has2) AW[((sg + 2) * N_NODE + i) * DIM + o2] = a2;
}
__global__ void k_aw(const int* fl, const void* adjs, const void* Wr,
                     const void* Wu, const void* Wh, float* AW) {
    if (*fl) aw_body<true>(adjs, Wr, Wu, Wh, AW);
    else     aw_body<false>(adjs, Wr, Wu, Wh, AW);
}

// final_wv -> out at element offset SEQ*N_NODE*DIM
template<bool ISB>
__device__ void wvout_body(const float* wv, void* out) {
    int idx = blockIdx.x * 256 + threadIdx.x;
    if (idx < NH * DIM * DIM)
        stv<ISB>(out, (size_t)SEQ * N_NODE * DIM + idx, wv[idx]);
}
__global__ void k_wvout(const int* fl, const float* wv, void* out) {
    if (*fl) wvout_body<true>(wv, out); else wvout_body<false>(wv, out);
}

extern "C" void kernel_launch(void* const* d_in, const int* in_sizes, int n_in,
                              void* d_out, int out_size, void* d_ws, size_t ws_size,
                              hipStream_t stream) {
    const void* adjs    = d_in[0];
    const void* feats   = d_in[1];
    const void* init_wv = d_in[3];
    const void* W1 = d_in[4];
    const void* b1 = d_in[5];
    const void* W2 = d_in[10];
    const void* b2 = d_in[11];
    const void* Wr = d_in[16];
    const void* Ur = d_in[17];
    const void* Pr = d_in[18];
    const void* br = d_in[19];
    const void* Wu = d_in[20];
    const void* Uu = d_in[21];
    const void* Pu = d_in[22];
    const void* bu = d_in[23];
    const void* Wh = d_in[24];
    const void* Uh = d_in[25];
    const void* Ph = d_in[26];
    const void* bh = d_in[27];

    // ---- workspace layout (floats), with live-range overlay ----
    // AW (7,372,800; phases aw->pg) overlays [Hbuf..rwbuf+pad] which are dead
    // by then (GAT done; ubuf/rwbuf only used after pg).
    int*   flag = (int*)d_ws;
    float* base = (float*)d_ws;
    float* Hbuf = base + 64;              // 3,276,800
    float* Obuf = Hbuf + 3276800;         // 3,276,800
    float* W1t  = Obuf + 3276800;         // 40,000
    float* W2t  = W1t + 40000;            // 40,000
    float* b1f  = W2t + 40000;            // 256
    float* b2f  = b1f + 256;              // 256
    float* ubuf = b2f + 256;              // 320,000
    float* rwbuf= ubuf + 320000;          // 320,000
    float* AW   = base + 64;              // 7,372,800 overlay (end 7,372,864)
    float* Utf  = base + 7372864;         // 120,000
    float* bgf  = Utf + 120000;           // 120,000
    float* G    = bgf + 120000;           // 360,000
    float* wv   = G + 360000;             // 320,000
    // total 8,292,864 floats = 33.2 MB

    const int M = SEQ * N_NODE;           // 16384

    k_detect<<<1, 256, 0, stream>>>(feats, flag);
    k_prepw<<<315, 256, 0, stream>>>(flag, W1, b1, W2, b2, W1t, W2t, b1f, b2f);
    k_prepu<<<(240000 + NH * DIM * DIM + 255) / 256, 256, 0, stream>>>(
        flag, Ur, Uu, Uh, br, bu, bh, init_wv, Utf, bgf, wv);

    // ---- GAT branch ----
    {
        dim3 g(4, M / 64);
        k_gemm_e0<<<g, 256, 0, stream>>>(flag, 1, feats, DIM, W1t, M, DIM, b1f, Hbuf);
        k_gemm_e0<<<g, 256, 0, stream>>>(flag, 0, Hbuf, DIM, W2t, M, DIM, b2f, Obuf);
    }
    k_softmax<<<SEQ * N_NODE, 64, 0, stream>>>(flag, Obuf, d_out);

    // ---- GRU branch ----
    {
        dim3 g(N_NODE, 3);
        k_aw<<<g, 256, 0, stream>>>(flag, adjs, Wr, Wu, Wh, AW);
    }
    {
        dim3 g(4, 4, 9);
        k_pggemm<<<g, 256, 0, stream>>>(flag, Pr, Pu, Ph, AW, bgf, G);
    }
    {
        dim3 g(4, NH * DIM / 64);   // (4, 25)
        for (int s = 0; s < 3; s++) {
            const float* Gr = G + (size_t)(s * 3 + 0) * DIM * DIM;
            const float* Gu = G + (size_t)(s * 3 + 1) * DIM * DIM;
            const float* Gh = G + (size_t)(s * 3 + 2) * DIM * DIM;
            k_gemm_e1<<<g, 256, 0, stream>>>(wv, Utf + 0,      Gr, wv, rwbuf);
            k_gemm_e2<<<g, 256, 0, stream>>>(wv, Utf + 40000,  Gu, ubuf);
            k_gemm_e3<<<g, 256, 0, stream>>>(rwbuf, Utf + 80000, Gh, ubuf, wv);
        }
    }
    k_wvout<<<(NH * DIM * DIM + 255) / 256, 256, 0, stream>>>(flag, wv, d_out);
}

// Round 5
// 958.836 us; speedup vs baseline: 1.9690x; 1.2748x over previous
//
#include <hip/hip_runtime.h>
#include <hip/hip_bf16.h>
#include <math.h>

typedef __hip_bfloat16 bf16;

#define N_NODE 4096
#define DIM 200
#define NH 8
#define SEQ 4

__device__ __forceinline__ float eluf(float x) { return x > 0.f ? x : expm1f(x); }
__device__ __forceinline__ float sigm(float x) { return 1.f / (1.f + expf(-x)); }

template<bool ISB>
__device__ __forceinline__ float ldv(const void* p, size_t i) {
    if (ISB) return __bfloat162float(((const bf16*)p)[i]);
    else     return ((const float*)p)[i];
}
template<bool ISB>
__device__ __forceinline__ void stv(void* p, size_t i, float v) {
    if (ISB) ((bf16*)p)[i] = __float2bfloat16(v);
    else     ((float*)p)[i] = v;
}

// Detect input dtype from feats (values ~ N(0,1)). See round-1/2 analysis.
__global__ void k_detect(const void* feats, int* flag) {
    __shared__ int cnt;
    if (threadIdx.x == 0) cnt = 0;
    __syncthreads();
    const unsigned short* u = (const unsigned short*)feats;
    unsigned short v = u[2 * threadIdx.x];
    int e = (v >> 7) & 0xFF;
    if (e >= 100 && e <= 140) atomicAdd(&cnt, 1);
    __syncthreads();
    if (threadIdx.x == 0) *flag = (cnt >= 128) ? 1 : 0;
}

// ---------------- tiled GEMM core ----------------
// C-tile 64x64/block, 256 threads, 4x4 micro-tile, K-chunk 8, [kbeg,kend).
// As padded [8][68]: staging-store banks ar+{0,8,16,24} -> conflict-free.
// Epilogues:
//  0: C = elu(acc + X1[col])
//  3: wv update: C = (1-u)*C + u*tanh(X1[(row%200)*200+col]+acc), u=X2
//  4: atomicAdd(C, acc)   (K-split P@AW; C pre-init with bias)
template<int EPI, bool AISB>
__device__ void gemm_body(const void* A, int lda, const float* B, int M, int K,
                          int kbeg, int kend,
                          const float* X1, const float* X2, float* C,
                          int row0, int c0) {
    const int N = DIM;
    int tid = threadIdx.x;
    int tx = tid & 15, ty = tid >> 4;
    __shared__ float As[8][68];
    __shared__ float Bs[8][64];
    float acc[4][4] = {};
    int ar = tid >> 2;            // 0..63
    int ak = (tid & 3) * 2;       // 0,2,4,6
    int bk = tid >> 5;            // 0..7
    int bc = (tid & 31) * 2;      // 0..62
    for (int k0 = kbeg; k0 < kend; k0 += 8) {
        float a0 = 0.f, a1 = 0.f;
        if (row0 + ar < M) {
            size_t base = (size_t)(row0 + ar) * lda + k0 + ak;
            a0 = ldv<AISB>(A, base);
            a1 = ldv<AISB>(A, base + 1);
        }
        float b0 = (c0 + bc     < N) ? B[(size_t)(k0 + bk) * N + c0 + bc]     : 0.f;
        float b1 = (c0 + bc + 1 < N) ? B[(size_t)(k0 + bk) * N + c0 + bc + 1] : 0.f;
        __syncthreads();
        As[ak][ar] = a0; As[ak + 1][ar] = a1;
        Bs[bk][bc] = b0; Bs[bk][bc + 1]  = b1;
        __syncthreads();
#pragma unroll
        for (int kk = 0; kk < 8; kk++) {
            float av[4], bv[4];
            *(float4*)av = *(const float4*)&As[kk][ty * 4];
            *(float4*)bv = *(const float4*)&Bs[kk][tx * 4];
#pragma unroll
            for (int i = 0; i < 4; i++)
#pragma unroll
                for (int j = 0; j < 4; j++) acc[i][j] += av[i] * bv[j];
        }
    }
#pragma unroll
    for (int i = 0; i < 4; i++) {
        int row = row0 + ty * 4 + i;
        if (row >= M) continue;
        int a200 = row - (row / 200) * 200;
#pragma unroll
        for (int j = 0; j < 4; j++) {
            int col = c0 + tx * 4 + j;
            if (col >= N) continue;
            float v = acc[i][j];
            size_t ci = (size_t)row * 200 + col;
            if (EPI == 0) {
                C[ci] = eluf(v + X1[col]);
            } else if (EPI == 3) {
                float uu = X2[ci];
                float hc = tanhf(X1[a200 * 200 + col] + v);
                C[ci] = (1.f - uu) * C[ci] + uu * hc;
            } else {
                atomicAdd(&C[ci], v);
            }
        }
    }
}

// fused r+u gate GEMM: A=wv [1600x200], Br=Ur, Bu=Uu (both [200x200] f32).
// rw = sigm(Gr[a200,col]+accR) * wv[ci];  u = sigm(Gu[a200,col]+accU)
__global__ __launch_bounds__(256) void k_gemm_e12(const float* A,
        const float* Br, const float* Bu, const float* Gr, const float* Gu,
        float* rw, float* u) {
    const int M = NH * DIM, K = DIM, N = DIM;
    int row0 = blockIdx.y * 64, c0 = blockIdx.x * 64;
    int tid = threadIdx.x;
    int tx = tid & 15, ty = tid >> 4;
    __shared__ float As[8][68];
    __shared__ float Bsr[8][64];
    __shared__ float Bsu[8][64];
    float accR[4][4] = {}, accU[4][4] = {};
    int ar = tid >> 2, ak = (tid & 3) * 2;
    int bk = tid >> 5, bc = (tid & 31) * 2;
    for (int k0 = 0; k0 < K; k0 += 8) {
        float a0 = 0.f, a1 = 0.f;
        if (row0 + ar < M) {
            size_t base = (size_t)(row0 + ar) * K + k0 + ak;
            a0 = A[base]; a1 = A[base + 1];
        }
        float br0 = 0.f, br1 = 0.f, bu0 = 0.f, bu1 = 0.f;
        if (c0 + bc < N) {
            br0 = Br[(size_t)(k0 + bk) * N + c0 + bc];
            bu0 = Bu[(size_t)(k0 + bk) * N + c0 + bc];
        }
        if (c0 + bc + 1 < N) {
            br1 = Br[(size_t)(k0 + bk) * N + c0 + bc + 1];
            bu1 = Bu[(size_t)(k0 + bk) * N + c0 + bc + 1];
        }
        __syncthreads();
        As[ak][ar] = a0; As[ak + 1][ar] = a1;
        Bsr[bk][bc] = br0; Bsr[bk][bc + 1] = br1;
        Bsu[bk][bc] = bu0; Bsu[bk][bc + 1] = bu1;
        __syncthreads();
#pragma unroll
        for (int kk = 0; kk < 8; kk++) {
            float av[4], bvr[4], bvu[4];
            *(float4*)av  = *(const float4*)&As[kk][ty * 4];
            *(float4*)bvr = *(const float4*)&Bsr[kk][tx * 4];
            *(float4*)bvu = *(const float4*)&Bsu[kk][tx * 4];
#pragma unroll
            for (int i = 0; i < 4; i++)
#pragma unroll
                for (int j = 0; j < 4; j++) {
                    accR[i][j] += av[i] * bvr[j];
                    accU[i][j] += av[i] * bvu[j];
                }
        }
    }
#pragma unroll
    for (int i = 0; i < 4; i++) {
        int row = row0 + ty * 4 + i;
        if (row >= M) continue;
        int a200 = row - (row / 200) * 200;
#pragma unroll
        for (int j = 0; j < 4; j++) {
            int col = c0 + tx * 4 + j;
            if (col >= N) continue;
            size_t ci = (size_t)row * 200 + col;
            rw[ci] = sigm(Gr[a200 * 200 + col] + accR[i][j]) * A[ci];
            u[ci]  = sigm(Gu[a200 * 200 + col] + accU[i][j]);
        }
    }
}

__global__ __launch_bounds__(256) void k_gemm_e0(const int* fl, int useIsb,
        const void* A, int lda, const float* B, int M, int K,
        const float* bias, float* C) {
    int row0 = blockIdx.y * 64, c0 = blockIdx.x * 64;
    if (useIsb && *fl) gemm_body<0, true >(A, lda, B, M, K, 0, K, bias, nullptr, C, row0, c0);
    else               gemm_body<0, false>(A, lda, B, M, K, 0, K, bias, nullptr, C, row0, c0);
}
__global__ __launch_bounds__(256) void k_gemm_e3(const float* A, const float* B,
        const float* G0, const float* U, float* WV) {
    gemm_body<3, false>(A, DIM, B, NH * DIM, DIM, 0, DIM, G0, U, WV,
                        blockIdx.y * 64, blockIdx.x * 64);
}

// G init: G[sg][a][b] = bias_g[a][b]
__global__ void k_ginit(const float* bgf, float* G) {
    int idx = blockIdx.x * 256 + threadIdx.x;
    if (idx >= 9 * DIM * DIM) return;
    int sg = idx / (DIM * DIM), r = idx - sg * (DIM * DIM);
    int g = sg - (sg / 3) * 3;
    G[idx] = bgf[(size_t)g * DIM * DIM + r];
}

// K-split P@AW: z = sg*8 + split; atomicAdd into pre-initialized G
__global__ __launch_bounds__(256) void k_pggemm(const int* fl,
        const void* P0, const void* P1, const void* P2,
        const float* AW, float* G) {
    int z = blockIdx.z;
    int sg = z >> 3, split = z & 7;
    int g = sg - (sg / 3) * 3;
    const void* A = (g == 0) ? P0 : (g == 1) ? P1 : P2;
    const float* B = AW + (size_t)sg * N_NODE * DIM;
    float* C = G + (size_t)sg * DIM * DIM;
    int row0 = blockIdx.y * 64, c0 = blockIdx.x * 64;
    int kbeg = split * (N_NODE / 8), kend = kbeg + N_NODE / 8;
    if (*fl) gemm_body<4, true >(A, N_NODE, B, DIM, N_NODE, kbeg, kend, nullptr, nullptr, C, row0, c0);
    else     gemm_body<4, false>(A, N_NODE, B, DIM, N_NODE, kbeg, kend, nullptr, nullptr, C, row0, c0);
}

// ---------------- prep kernels ----------------

template<bool ISB>
__device__ void prepw_body(const void* W1, const void* b1, const void* W2,
                           const void* b2, float* W1t, float* W2t,
                           float* b1f, float* b2f) {
    int idx = blockIdx.x * 256 + threadIdx.x;
    if (idx < 40000) {
        int k = idx / 200, n = idx % 200;
        W1t[idx] = ldv<ISB>(W1, (size_t)n * 200 + k);
    } else if (idx < 80000) {
        int r = idx - 40000;
        int k = r / 200, n = r % 200;
        float s = 0.f;
        for (int h = 0; h < NH; h++) s += ldv<ISB>(W2, (size_t)n * 1600 + h * 200 + k);
        W2t[r] = s;
    } else if (idx < 80256) {
        int j = idx - 80000;
        b1f[j] = (j < 200) ? ldv<ISB>(b1, j) : 0.f;
    } else if (idx < 80512) {
        int j = idx - 80256;
        b2f[j] = (j < 200) ? ldv<ISB>(b2, j) : 0.f;
    }
}
__global__ void k_prepw(const int* fl, const void* W1, const void* b1,
                        const void* W2, const void* b2, float* W1t, float* W2t,
                        float* b1f, float* b2f) {
    if (*fl) prepw_body<true >(W1, b1, W2, b2, W1t, W2t, b1f, b2f);
    else     prepw_body<false>(W1, b1, W2, b2, W1t, W2t, b1f, b2f);
}

template<bool ISB>
__device__ void prepu_body(const void* Ur, const void* Uu, const void* Uh,
                           const void* br, const void* bu, const void* bh,
                           const void* iwv, float* Utf, float* bgf, float* wv) {
    int idx = blockIdx.x * 256 + threadIdx.x;
    if (idx < 120000) {
        int g = idx / 40000, r = idx - g * 40000;
        const void* U = (g == 0) ? Ur : (g == 1) ? Uu : Uh;
        Utf[idx] = ldv<ISB>(U, r);
    } else if (idx < 240000) {
        int j = idx - 120000;
        int g = j / 40000, r = j - g * 40000;
        const void* bb = (g == 0) ? br : (g == 1) ? bu : bh;
        bgf[j] = ldv<ISB>(bb, r);
    } else if (idx < 240000 + NH * DIM * DIM) {
        int j = idx - 240000;
        wv[j] = ldv<ISB>(iwv, j);
    }
}
__global__ void k_prepu(const int* fl, const void* Ur, const void* Uu, const void* Uh,
                        const void* br, const void* bu, const void* bh,
                        const void* iwv, float* Utf, float* bgf, float* wv) {
    if (*fl) prepu_body<true >(Ur, Uu, Uh, br, bu, bh, iwv, Utf, bgf, wv);
    else     prepu_body<false>(Ur, Uu, Uh, br, bu, bh, iwv, Utf, bgf, wv);
}

// ---------------- softmax (verified) ----------------
template<bool ISB>
__device__ void softmax_body(const float* O, void* out) {
    int t = blockIdx.x >> 12;
    int i = blockIdx.x & (N_NODE - 1);
    const float* ob = O + (size_t)t * N_NODE * DIM;
    int lane = threadIdx.x;
    int j0 = lane, j1 = lane + 64, j2 = lane + 128, j3 = lane + 192;
    bool h3 = (j3 < DIM);
    float v0 = ob[(size_t)j0 * N_NODE + i];
    float v1 = ob[(size_t)j1 * N_NODE + i];
    float v2 = ob[(size_t)j2 * N_NODE + i];
    float v3 = h3 ? ob[(size_t)j3 * N_NODE + i] : -1e30f;
    float m = fmaxf(fmaxf(v0, v1), fmaxf(v2, v3));
    for (int off = 32; off > 0; off >>= 1) m = fmaxf(m, __shfl_xor(m, off));
    float e0 = expf(v0 - m), e1 = expf(v1 - m), e2 = expf(v2 - m);
    float e3 = h3 ? expf(v3 - m) : 0.f;
    float s = e0 + e1 + e2 + e3;
    for (int off = 32; off > 0; off >>= 1) s += __shfl_xor(s, off);
    float inv = 1.f / s;
    size_t base = ((size_t)t * N_NODE + i) * DIM;
    stv<ISB>(out, base + j0, e0 * inv);
    stv<ISB>(out, base + j1, e1 * inv);
    stv<ISB>(out, base + j2, e2 * inv);
    if (h3) stv<ISB>(out, base + j3, e3 * inv);
}
__global__ void k_softmax(const int* fl, const float* O, void* out) {
    if (*fl) softmax_body<true>(O, out); else softmax_body<false>(O, out);
}

// ---------------- sparse A@W (verified) ----------------
template<bool ISB>
__device__ void aw_body(const void* adjs, const void* Wr, const void* Wu,
                        const void* Wh, float* AW) {
    int i = blockIdx.x;
    int s = blockIdx.y;
    size_t arow = ((size_t)(s + 1) * N_NODE + i) * N_NODE;
    __shared__ int   s_k[256];
    __shared__ float s_v[256];
    __shared__ int   s_cnt;
    int tid = threadIdx.x;
    int c0 = tid, c1 = tid + 256, c2 = tid + 512;
    int g0 = c0 / DIM, o0 = c0 % DIM;
    int g1 = c1 / DIM, o1 = c1 % DIM;
    bool has2 = (c2 < 600);
    int o2 = has2 ? (c2 % DIM) : 0;
    const void* w0 = (g0 == 0) ? Wr : Wu;
    const void* w1 = (g1 == 1) ? Wu : Wh;
    const void* w2 = Wh;
    float a0 = 0.f, a1 = 0.f, a2 = 0.f;
    for (int base = 0; base < N_NODE; base += 256) {
        if (tid == 0) s_cnt = 0;
        __syncthreads();
        float av = ldv<ISB>(adjs, arow + base + tid);
        if (av != 0.f) {
            int p = atomicAdd(&s_cnt, 1);
            s_k[p] = base + tid; s_v[p] = av;
        }
        __syncthreads();
        int n = s_cnt;
        for (int e = 0; e < n; e++) {
            int k = s_k[e]; float v = s_v[e];
            a0 += v * ldv<ISB>(w0, (size_t)k * DIM + o0);
            a1 += v * ldv<ISB>(w1, (size_t)k * DIM + o1);
            if (has2) a2 += v * ldv<ISB>(w2, (size_t)k * DIM + o2);
        }
        __syncthreads();
    }
    size_t sg = (size_t)s * 3;
    AW[((sg + g0) * N_NODE + i) * DIM + o0] = a0;
    AW[((sg + g1) * N_NODE + i) * DIM + o1] = a1;
    if (has2) AW[((sg + 2) * N_NODE + i) * DIM + o2] = a2;
}
__global__ void k_aw(const int* fl, const void* adjs, const void* Wr,
                     const void* Wu, const void* Wh, float* AW) {
    if (*fl) aw_body<true>(adjs, Wr, Wu, Wh, AW);
    else     aw_body<false>(adjs, Wr, Wu, Wh, AW);
}

template<bool ISB>
__device__ void wvout_body(const float* wv, void* out) {
    int idx = blockIdx.x * 256 + threadIdx.x;
    if (idx < NH * DIM * DIM)
        stv<ISB>(out, (size_t)SEQ * N_NODE * DIM + idx, wv[idx]);
}
__global__ void k_wvout(const int* fl, const float* wv, void* out) {
    if (*fl) wvout_body<true>(wv, out); else wvout_body<false>(wv, out);
}

extern "C" void kernel_launch(void* const* d_in, const int* in_sizes, int n_in,
                              void* d_out, int out_size, void* d_ws, size_t ws_size,
                              hipStream_t stream) {
    const void* adjs    = d_in[0];
    const void* feats   = d_in[1];
    const void* init_wv = d_in[3];
    const void* W1 = d_in[4];
    const void* b1 = d_in[5];
    const void* W2 = d_in[10];
    const void* b2 = d_in[11];
    const void* Wr = d_in[16];
    const void* Ur = d_in[17];
    const void* Pr = d_in[18];
    const void* Wu = d_in[20];
    const void* Uu = d_in[21];
    const void* Pu = d_in[22];
    const void* bu = d_in[23];
    const void* br = d_in[19];
    const void* Wh = d_in[24];
    const void* Uh = d_in[25];
    const void* Ph = d_in[26];
    const void* bh = d_in[27];

    // ---- workspace layout (floats), live-range overlay ----
    int*   flag = (int*)d_ws;
    float* base = (float*)d_ws;
    float* Hbuf = base + 64;              // 3,276,800
    float* Obuf = Hbuf + 3276800;         // 3,276,800
    float* W1t  = Obuf + 3276800;         // 40,000
    float* W2t  = W1t + 40000;            // 40,000
    float* b1f  = W2t + 40000;            // 256
    float* b2f  = b1f + 256;              // 256
    float* ubuf = b2f + 256;              // 320,000
    float* rwbuf= ubuf + 320000;          // 320,000
    float* AW   = base + 64;              // 7,372,800 overlay (dead ranges)
    float* Utf  = base + 7372864;         // 120,000
    float* bgf  = Utf + 120000;           // 120,000
    float* G    = bgf + 120000;           // 360,000
    float* wv   = G + 360000;             // 320,000
    // total 8,292,864 floats = 33.2 MB

    const int M = SEQ * N_NODE;           // 16384

    k_detect<<<1, 256, 0, stream>>>(feats, flag);
    k_prepw<<<315, 256, 0, stream>>>(flag, W1, b1, W2, b2, W1t, W2t, b1f, b2f);
    k_prepu<<<(240000 + NH * DIM * DIM + 255) / 256, 256, 0, stream>>>(
        flag, Ur, Uu, Uh, br, bu, bh, init_wv, Utf, bgf, wv);

    // ---- GAT branch ----
    {
        dim3 g(4, M / 64);
        k_gemm_e0<<<g, 256, 0, stream>>>(flag, 1, feats, DIM, W1t, M, DIM, b1f, Hbuf);
        k_gemm_e0<<<g, 256, 0, stream>>>(flag, 0, Hbuf, DIM, W2t, M, DIM, b2f, Obuf);
    }
    k_softmax<<<SEQ * N_NODE, 64, 0, stream>>>(flag, Obuf, d_out);

    // ---- GRU branch ----
    {
        dim3 g(N_NODE, 3);
        k_aw<<<g, 256, 0, stream>>>(flag, adjs, Wr, Wu, Wh, AW);
    }
    k_ginit<<<(9 * DIM * DIM + 255) / 256, 256, 0, stream>>>(bgf, G);
    {
        dim3 g(4, 4, 72);   // 1152 blocks: 16 C-tiles x 9 (s,g) x 8 K-splits
        k_pggemm<<<g, 256, 0, stream>>>(flag, Pr, Pu, Ph, AW, G);
    }
    {
        dim3 g(4, NH * DIM / 64);   // (4, 25)
        for (int s = 0; s < 3; s++) {
            const float* Gr = G + (size_t)(s * 3 + 0) * DIM * DIM;
            const float* Gu = G + (size_t)(s * 3 + 1) * DIM * DIM;
            const float* Gh = G + (size_t)(s * 3 + 2) * DIM * DIM;
            k_gemm_e12<<<g, 256, 0, stream>>>(wv, Utf + 0, Utf + 40000, Gr, Gu, rwbuf, ubuf);
            k_gemm_e3<<<g, 256, 0, stream>>>(rwbuf, Utf + 80000, Gh, ubuf, wv);
        }
    }
    k_wvout<<<(NH * DIM * DIM + 255) / 256, 256, 0, stream>>>(flag, wv, d_out);
}

// Round 6
// 892.431 us; speedup vs baseline: 2.1155x; 1.0744x over previous
//
#include <hip/hip_runtime.h>
#include <hip/hip_bf16.h>
#include <math.h>

typedef __hip_bfloat16 bf16;

#define N_NODE 4096
#define DIM 200
#define NH 8
#define SEQ 4

__device__ __forceinline__ float eluf(float x) { return x > 0.f ? x : expm1f(x); }
__device__ __forceinline__ float sigm(float x) { return 1.f / (1.f + expf(-x)); }

template<bool ISB>
__device__ __forceinline__ float ldv(const void* p, size_t i) {
    if (ISB) return __bfloat162float(((const bf16*)p)[i]);
    else     return ((const float*)p)[i];
}
template<bool ISB>
__device__ __forceinline__ void stv(void* p, size_t i, float v) {
    if (ISB) ((bf16*)p)[i] = __float2bfloat16(v);
    else     ((float*)p)[i] = v;
}

// Detect input dtype from feats (values ~ N(0,1)). See round-1/2 analysis.
__global__ void k_detect(const void* feats, int* flag) {
    __shared__ int cnt;
    if (threadIdx.x == 0) cnt = 0;
    __syncthreads();
    const unsigned short* u = (const unsigned short*)feats;
    unsigned short v = u[2 * threadIdx.x];
    int e = (v >> 7) & 0xFF;
    if (e >= 100 && e <= 140) atomicAdd(&cnt, 1);
    __syncthreads();
    if (threadIdx.x == 0) *flag = (cnt >= 128) ? 1 : 0;
}

// ---------------- tiled GEMM core (verified round 5) ----------------
template<int EPI, bool AISB>
__device__ void gemm_body(const void* A, int lda, const float* B, int M, int K,
                          int kbeg, int kend,
                          const float* X1, const float* X2, float* C,
                          int row0, int c0) {
    const int N = DIM;
    int tid = threadIdx.x;
    int tx = tid & 15, ty = tid >> 4;
    __shared__ float As[8][68];
    __shared__ float Bs[8][64];
    float acc[4][4] = {};
    int ar = tid >> 2;
    int ak = (tid & 3) * 2;
    int bk = tid >> 5;
    int bc = (tid & 31) * 2;
    for (int k0 = kbeg; k0 < kend; k0 += 8) {
        float a0 = 0.f, a1 = 0.f;
        if (row0 + ar < M) {
            size_t base = (size_t)(row0 + ar) * lda + k0 + ak;
            a0 = ldv<AISB>(A, base);
            a1 = ldv<AISB>(A, base + 1);
        }
        float b0 = (c0 + bc     < N) ? B[(size_t)(k0 + bk) * N + c0 + bc]     : 0.f;
        float b1 = (c0 + bc + 1 < N) ? B[(size_t)(k0 + bk) * N + c0 + bc + 1] : 0.f;
        __syncthreads();
        As[ak][ar] = a0; As[ak + 1][ar] = a1;
        Bs[bk][bc] = b0; Bs[bk][bc + 1]  = b1;
        __syncthreads();
#pragma unroll
        for (int kk = 0; kk < 8; kk++) {
            float av[4], bv[4];
            *(float4*)av = *(const float4*)&As[kk][ty * 4];
            *(float4*)bv = *(const float4*)&Bs[kk][tx * 4];
#pragma unroll
            for (int i = 0; i < 4; i++)
#pragma unroll
                for (int j = 0; j < 4; j++) acc[i][j] += av[i] * bv[j];
        }
    }
#pragma unroll
    for (int i = 0; i < 4; i++) {
        int row = row0 + ty * 4 + i;
        if (row >= M) continue;
        int a200 = row - (row / 200) * 200;
#pragma unroll
        for (int j = 0; j < 4; j++) {
            int col = c0 + tx * 4 + j;
            if (col >= N) continue;
            float v = acc[i][j];
            size_t ci = (size_t)row * 200 + col;
            if (EPI == 0) {
                C[ci] = eluf(v + X1[col]);
            } else if (EPI == 3) {
                float uu = X2[ci];
                float hc = tanhf(X1[a200 * 200 + col] + v);
                C[ci] = (1.f - uu) * C[ci] + uu * hc;
            } else {
                atomicAdd(&C[ci], v);
            }
        }
    }
}

// fused r+u gate GEMM (verified round 5)
__global__ __launch_bounds__(256) void k_gemm_e12(const float* A,
        const float* Br, const float* Bu, const float* Gr, const float* Gu,
        float* rw, float* u) {
    const int M = NH * DIM, K = DIM, N = DIM;
    int row0 = blockIdx.y * 64, c0 = blockIdx.x * 64;
    int tid = threadIdx.x;
    int tx = tid & 15, ty = tid >> 4;
    __shared__ float As[8][68];
    __shared__ float Bsr[8][64];
    __shared__ float Bsu[8][64];
    float accR[4][4] = {}, accU[4][4] = {};
    int ar = tid >> 2, ak = (tid & 3) * 2;
    int bk = tid >> 5, bc = (tid & 31) * 2;
    for (int k0 = 0; k0 < K; k0 += 8) {
        float a0 = 0.f, a1 = 0.f;
        if (row0 + ar < M) {
            size_t base = (size_t)(row0 + ar) * K + k0 + ak;
            a0 = A[base]; a1 = A[base + 1];
        }
        float br0 = 0.f, br1 = 0.f, bu0 = 0.f, bu1 = 0.f;
        if (c0 + bc < N) {
            br0 = Br[(size_t)(k0 + bk) * N + c0 + bc];
            bu0 = Bu[(size_t)(k0 + bk) * N + c0 + bc];
        }
        if (c0 + bc + 1 < N) {
            br1 = Br[(size_t)(k0 + bk) * N + c0 + bc + 1];
            bu1 = Bu[(size_t)(k0 + bk) * N + c0 + bc + 1];
        }
        __syncthreads();
        As[ak][ar] = a0; As[ak + 1][ar] = a1;
        Bsr[bk][bc] = br0; Bsr[bk][bc + 1] = br1;
        Bsu[bk][bc] = bu0; Bsu[bk][bc + 1] = bu1;
        __syncthreads();
#pragma unroll
        for (int kk = 0; kk < 8; kk++) {
            float av[4], bvr[4], bvu[4];
            *(float4*)av  = *(const float4*)&As[kk][ty * 4];
            *(float4*)bvr = *(const float4*)&Bsr[kk][tx * 4];
            *(float4*)bvu = *(const float4*)&Bsu[kk][tx * 4];
#pragma unroll
            for (int i = 0; i < 4; i++)
#pragma unroll
                for (int j = 0; j < 4; j++) {
                    accR[i][j] += av[i] * bvr[j];
                    accU[i][j] += av[i] * bvu[j];
                }
        }
    }
#pragma unroll
    for (int i = 0; i < 4; i++) {
        int row = row0 + ty * 4 + i;
        if (row >= M) continue;
        int a200 = row - (row / 200) * 200;
#pragma unroll
        for (int j = 0; j < 4; j++) {
            int col = c0 + tx * 4 + j;
            if (col >= N) continue;
            size_t ci = (size_t)row * 200 + col;
            rw[ci] = sigm(Gr[a200 * 200 + col] + accR[i][j]) * A[ci];
            u[ci]  = sigm(Gu[a200 * 200 + col] + accU[i][j]);
        }
    }
}

__global__ __launch_bounds__(256) void k_gemm_e0(const int* fl, int useIsb,
        const void* A, int lda, const float* B, int M, int K,
        const float* bias, float* C) {
    int row0 = blockIdx.y * 64, c0 = blockIdx.x * 64;
    if (useIsb && *fl) gemm_body<0, true >(A, lda, B, M, K, 0, K, bias, nullptr, C, row0, c0);
    else               gemm_body<0, false>(A, lda, B, M, K, 0, K, bias, nullptr, C, row0, c0);
}
__global__ __launch_bounds__(256) void k_gemm_e3(const float* A, const float* B,
        const float* G0, const float* U, float* WV) {
    gemm_body<3, false>(A, DIM, B, NH * DIM, DIM, 0, DIM, G0, U, WV,
                        blockIdx.y * 64, blockIdx.x * 64);
}

__global__ void k_ginit(const float* bgf, float* G) {
    int idx = blockIdx.x * 256 + threadIdx.x;
    if (idx >= 9 * DIM * DIM) return;
    int sg = idx / (DIM * DIM), r = idx - sg * (DIM * DIM);
    int g = sg - (sg / 3) * 3;
    G[idx] = bgf[(size_t)g * DIM * DIM + r];
}

__global__ __launch_bounds__(256) void k_pggemm(const int* fl,
        const void* P0, const void* P1, const void* P2,
        const float* AW, float* G) {
    int z = blockIdx.z;
    int sg = z >> 3, split = z & 7;
    int g = sg - (sg / 3) * 3;
    const void* A = (g == 0) ? P0 : (g == 1) ? P1 : P2;
    const float* B = AW + (size_t)sg * N_NODE * DIM;
    float* C = G + (size_t)sg * DIM * DIM;
    int row0 = blockIdx.y * 64, c0 = blockIdx.x * 64;
    int kbeg = split * (N_NODE / 8), kend = kbeg + N_NODE / 8;
    if (*fl) gemm_body<4, true >(A, N_NODE, B, DIM, N_NODE, kbeg, kend, nullptr, nullptr, C, row0, c0);
    else     gemm_body<4, false>(A, N_NODE, B, DIM, N_NODE, kbeg, kend, nullptr, nullptr, C, row0, c0);
}

// ---------------- prep kernels (verified) ----------------
template<bool ISB>
__device__ void prepw_body(const void* W1, const void* b1, const void* W2,
                           const void* b2, float* W1t, float* W2t,
                           float* b1f, float* b2f) {
    int idx = blockIdx.x * 256 + threadIdx.x;
    if (idx < 40000) {
        int k = idx / 200, n = idx % 200;
        W1t[idx] = ldv<ISB>(W1, (size_t)n * 200 + k);
    } else if (idx < 80000) {
        int r = idx - 40000;
        int k = r / 200, n = r % 200;
        float s = 0.f;
        for (int h = 0; h < NH; h++) s += ldv<ISB>(W2, (size_t)n * 1600 + h * 200 + k);
        W2t[r] = s;
    } else if (idx < 80256) {
        int j = idx - 80000;
        b1f[j] = (j < 200) ? ldv<ISB>(b1, j) : 0.f;
    } else if (idx < 80512) {
        int j = idx - 80256;
        b2f[j] = (j < 200) ? ldv<ISB>(b2, j) : 0.f;
    }
}
__global__ void k_prepw(const int* fl, const void* W1, const void* b1,
                        const void* W2, const void* b2, float* W1t, float* W2t,
                        float* b1f, float* b2f) {
    if (*fl) prepw_body<true >(W1, b1, W2, b2, W1t, W2t, b1f, b2f);
    else     prepw_body<false>(W1, b1, W2, b2, W1t, W2t, b1f, b2f);
}

template<bool ISB>
__device__ void prepu_body(const void* Ur, const void* Uu, const void* Uh,
                           const void* br, const void* bu, const void* bh,
                           const void* iwv, float* Utf, float* bgf, float* wv) {
    int idx = blockIdx.x * 256 + threadIdx.x;
    if (idx < 120000) {
        int g = idx / 40000, r = idx - g * 40000;
        const void* U = (g == 0) ? Ur : (g == 1) ? Uu : Uh;
        Utf[idx] = ldv<ISB>(U, r);
    } else if (idx < 240000) {
        int j = idx - 120000;
        int g = j / 40000, r = j - g * 40000;
        const void* bb = (g == 0) ? br : (g == 1) ? bu : bh;
        bgf[j] = ldv<ISB>(bb, r);
    } else if (idx < 240000 + NH * DIM * DIM) {
        int j = idx - 240000;
        wv[j] = ldv<ISB>(iwv, j);
    }
}
__global__ void k_prepu(const int* fl, const void* Ur, const void* Uu, const void* Uh,
                        const void* br, const void* bu, const void* bh,
                        const void* iwv, float* Utf, float* bgf, float* wv) {
    if (*fl) prepu_body<true >(Ur, Uu, Uh, br, bu, bh, iwv, Utf, bgf, wv);
    else     prepu_body<false>(Ur, Uu, Uh, br, bu, bh, iwv, Utf, bgf, wv);
}

// ---------------- softmax: LDS-transposed, coalesced ----------------
// Block = 256 threads, handles 64 nodes of one t. Tile [200][65] pad -> no
// bank conflicts on transpose read; global reads/writes fully coalesced.
template<bool ISB>
__device__ void softmax_body(const float* O, void* out) {
    __shared__ float tile[200 * 65];
    __shared__ float pm[4 * 64];
    __shared__ float ps[4 * 64];
    __shared__ float sm_m[64];
    __shared__ float sm_inv[64];
    int t = blockIdx.y;
    int i0 = blockIdx.x * 64;
    const float* ob = O + (size_t)t * N_NODE * DIM;
    int tid = threadIdx.x;
    // load [200][64] tile: wave covers 64 consecutive cols of one j-row
    for (int idx = tid; idx < 200 * 64; idx += 256) {
        int j = idx >> 6, c = idx & 63;
        tile[j * 65 + c] = ob[(size_t)j * N_NODE + i0 + c];
    }
    __syncthreads();
    int g = tid >> 6, lane = tid & 63;
    int j0 = g * 50, j1 = j0 + 50;
    float mp = -1e30f;
    for (int j = j0; j < j1; j++) mp = fmaxf(mp, tile[j * 65 + lane]);
    pm[g * 64 + lane] = mp;
    __syncthreads();
    if (tid < 64) {
        sm_m[tid] = fmaxf(fmaxf(pm[tid], pm[64 + tid]),
                          fmaxf(pm[128 + tid], pm[192 + tid]));
    }
    __syncthreads();
    float mv = sm_m[lane];
    float sp = 0.f;
    for (int j = j0; j < j1; j++) {
        float e = expf(tile[j * 65 + lane] - mv);
        tile[j * 65 + lane] = e;
        sp += e;
    }
    ps[g * 64 + lane] = sp;
    __syncthreads();
    if (tid < 64) {
        sm_inv[tid] = 1.f / (ps[tid] + ps[64 + tid] + ps[128 + tid] + ps[192 + tid]);
    }
    __syncthreads();
    size_t ob2 = ((size_t)t * N_NODE + i0) * DIM;
    for (int idx = tid; idx < 64 * 200; idx += 256) {
        int il = idx / 200, j = idx - il * 200;
        stv<ISB>(out, ob2 + (size_t)il * DIM + j, tile[j * 65 + il] * sm_inv[il]);
    }
}
__global__ __launch_bounds__(256) void k_softmax(const int* fl, const float* O, void* out) {
    if (*fl) softmax_body<true>(O, out); else softmax_body<false>(O, out);
}

// ---------------- sparse A@W: float4 adj scan ----------------
template<bool ISB>
__device__ void aw_body(const void* adjs, const void* Wr, const void* Wu,
                        const void* Wh, float* AW) {
    int i = blockIdx.x;
    int s = blockIdx.y;
    size_t arow = ((size_t)(s + 1) * N_NODE + i) * N_NODE;   // element index
    __shared__ int   s_k[256];
    __shared__ float s_v[256];
    __shared__ int   s_cnt;
    int tid = threadIdx.x;
    int c0 = tid, c1 = tid + 256, c2 = tid + 512;
    int g0 = c0 / DIM, o0 = c0 % DIM;
    int g1 = c1 / DIM, o1 = c1 % DIM;
    bool has2 = (c2 < 600);
    int o2 = has2 ? (c2 % DIM) : 0;
    const void* w0 = (g0 == 0) ? Wr : Wu;
    const void* w1 = (g1 == 1) ? Wu : Wh;
    const void* w2 = Wh;
    float a0 = 0.f, a1 = 0.f, a2 = 0.f;
    for (int base = 0; base < N_NODE; base += 1024) {
        if (tid == 0) s_cnt = 0;
        __syncthreads();
        float v4[4];
        int k0 = base + tid * 4;
        if (ISB) {
            const ushort4 u = *(const ushort4*)((const unsigned short*)adjs + arow + k0);
            v4[0] = __bfloat162float(*(const bf16*)&u.x);
            v4[1] = __bfloat162float(*(const bf16*)&u.y);
            v4[2] = __bfloat162float(*(const bf16*)&u.z);
            v4[3] = __bfloat162float(*(const bf16*)&u.w);
        } else {
            float4 f = *(const float4*)((const float*)adjs + arow + k0);
            v4[0] = f.x; v4[1] = f.y; v4[2] = f.z; v4[3] = f.w;
        }
#pragma unroll
        for (int q = 0; q < 4; q++) {
            if (v4[q] != 0.f) {
                int p = atomicAdd(&s_cnt, 1);
                if (p < 256) { s_k[p] = k0 + q; s_v[p] = v4[q]; }
            }
        }
        __syncthreads();
        int n = s_cnt < 256 ? s_cnt : 256;
        for (int e = 0; e < n; e++) {
            int k = s_k[e]; float v = s_v[e];
            a0 += v * ldv<ISB>(w0, (size_t)k * DIM + o0);
            a1 += v * ldv<ISB>(w1, (size_t)k * DIM + o1);
            if (has2) a2 += v * ldv<ISB>(w2, (size_t)k * DIM + o2);
        }
        __syncthreads();
    }
    size_t sg = (size_t)s * 3;
    AW[((sg + g0) * N_NODE + i) * DIM + o0] = a0;
    AW[((sg + g1) * N_NODE + i) * DIM + o1] = a1;
    if (has2) AW[((sg + 2) * N_NODE + i) * DIM + o2] = a2;
}
__global__ __launch_bounds__(256) void k_aw(const int* fl, const void* adjs,
        const void* Wr, const void* Wu, const void* Wh, float* AW) {
    if (*fl) aw_body<true>(adjs, Wr, Wu, Wh, AW);
    else     aw_body<false>(adjs, Wr, Wu, Wh, AW);
}

template<bool ISB>
__device__ void wvout_body(const float* wv, void* out) {
    int idx = blockIdx.x * 256 + threadIdx.x;
    if (idx < NH * DIM * DIM)
        stv<ISB>(out, (size_t)SEQ * N_NODE * DIM + idx, wv[idx]);
}
__global__ void k_wvout(const int* fl, const float* wv, void* out) {
    if (*fl) wvout_body<true>(wv, out); else wvout_body<false>(wv, out);
}

extern "C" void kernel_launch(void* const* d_in, const int* in_sizes, int n_in,
                              void* d_out, int out_size, void* d_ws, size_t ws_size,
                              hipStream_t stream) {
    const void* adjs    = d_in[0];
    const void* feats   = d_in[1];
    const void* init_wv = d_in[3];
    const void* W1 = d_in[4];
    const void* b1 = d_in[5];
    const void* W2 = d_in[10];
    const void* b2 = d_in[11];
    const void* Wr = d_in[16];
    const void* Ur = d_in[17];
    const void* Pr = d_in[18];
    const void* br = d_in[19];
    const void* Wu = d_in[20];
    const void* Uu = d_in[21];
    const void* Pu = d_in[22];
    const void* bu = d_in[23];
    const void* Wh = d_in[24];
    const void* Uh = d_in[25];
    const void* Ph = d_in[26];
    const void* bh = d_in[27];

    // ---- workspace layout (floats), live-range overlay ----
    int*   flag = (int*)d_ws;
    float* base = (float*)d_ws;
    float* Hbuf = base + 64;              // 3,276,800
    float* Obuf = Hbuf + 3276800;         // 3,276,800
    float* W1t  = Obuf + 3276800;         // 40,000
    float* W2t  = W1t + 40000;            // 40,000
    float* b1f  = W2t + 40000;            // 256
    float* b2f  = b1f + 256;              // 256
    float* ubuf = b2f + 256;              // 320,000
    float* rwbuf= ubuf + 320000;          // 320,000
    float* AW   = base + 64;              // 7,372,800 overlay (dead ranges)
    float* Utf  = base + 7372864;         // 120,000
    float* bgf  = Utf + 120000;           // 120,000
    float* G    = bgf + 120000;           // 360,000
    float* wv   = G + 360000;             // 320,000
    // total 8,292,864 floats = 33.2 MB

    const int M = SEQ * N_NODE;           // 16384

    k_detect<<<1, 256, 0, stream>>>(feats, flag);
    k_prepw<<<315, 256, 0, stream>>>(flag, W1, b1, W2, b2, W1t, W2t, b1f, b2f);
    k_prepu<<<(240000 + NH * DIM * DIM + 255) / 256, 256, 0, stream>>>(
        flag, Ur, Uu, Uh, br, bu, bh, init_wv, Utf, bgf, wv);

    // ---- GAT branch ----
    {
        dim3 g(4, M / 64);
        k_gemm_e0<<<g, 256, 0, stream>>>(flag, 1, feats, DIM, W1t, M, DIM, b1f, Hbuf);
        k_gemm_e0<<<g, 256, 0, stream>>>(flag, 0, Hbuf, DIM, W2t, M, DIM, b2f, Obuf);
    }
    {
        dim3 g(N_NODE / 64, SEQ);   // (64, 4)
        k_softmax<<<g, 256, 0, stream>>>(flag, Obuf, d_out);
    }

    // ---- GRU branch ----
    {
        dim3 g(N_NODE, 3);
        k_aw<<<g, 256, 0, stream>>>(flag, adjs, Wr, Wu, Wh, AW);
    }
    k_ginit<<<(9 * DIM * DIM + 255) / 256, 256, 0, stream>>>(bgf, G);
    {
        dim3 g(4, 4, 72);   // 16 C-tiles x 9 (s,g) x 8 K-splits
        k_pggemm<<<g, 256, 0, stream>>>(flag, Pr, Pu, Ph, AW, G);
    }
    {
        dim3 g(4, NH * DIM / 64);   // (4, 25)
        for (int s = 0; s < 3; s++) {
            const float* Gr = G + (size_t)(s * 3 + 0) * DIM * DIM;
            const float* Gu = G + (size_t)(s * 3 + 1) * DIM * DIM;
            const float* Gh = G + (size_t)(s * 3 + 2) * DIM * DIM;
            k_gemm_e12<<<g, 256, 0, stream>>>(wv, Utf + 0, Utf + 40000, Gr, Gu, rwbuf, ubuf);
            k_gemm_e3<<<g, 256, 0, stream>>>(rwbuf, Utf + 80000, Gh, ubuf, wv);
        }
    }
    k_wvout<<<(NH * DIM * DIM + 255) / 256, 256, 0, stream>>>(flag, wv, d_out);
}

// Round 7
// 792.800 us; speedup vs baseline: 2.3813x; 1.1257x over previous
//
#include <hip/hip_runtime.h>
#include <hip/hip_bf16.h>
#include <math.h>

typedef __hip_bfloat16 bf16;

#define N_NODE 4096
#define DIM 200
#define NH 8
#define SEQ 4

__device__ __forceinline__ float eluf(float x) { return x > 0.f ? x : expm1f(x); }
__device__ __forceinline__ float sigm(float x) { return 1.f / (1.f + expf(-x)); }

template<bool ISB>
__device__ __forceinline__ float ldv(const void* p, size_t i) {
    if (ISB) return __bfloat162float(((const bf16*)p)[i]);
    else     return ((const float*)p)[i];
}
template<bool ISB>
__device__ __forceinline__ void stv(void* p, size_t i, float v) {
    if (ISB) ((bf16*)p)[i] = __float2bfloat16(v);
    else     ((float*)p)[i] = v;
}
// bf16x2 unpack from a packed u32 (no convert instructions needed)
__device__ __forceinline__ float bflo(unsigned u) { return __uint_as_float((u & 0xffffu) << 16); }
__device__ __forceinline__ float bfhi(unsigned u) { return __uint_as_float(u & 0xffff0000u); }

// Detect input dtype from feats (values ~ N(0,1)). See round-1/2 analysis.
__global__ void k_detect(const void* feats, int* flag) {
    __shared__ int cnt;
    if (threadIdx.x == 0) cnt = 0;
    __syncthreads();
    const unsigned short* u = (const unsigned short*)feats;
    unsigned short v = u[2 * threadIdx.x];
    int e = (v >> 7) & 0xFF;
    if (e >= 100 && e <= 140) atomicAdd(&cnt, 1);
    __syncthreads();
    if (threadIdx.x == 0) *flag = (cnt >= 128) ? 1 : 0;
}

// ---------------- tiled GEMM core, software-pipelined ----------------
// C-tile 64x64/block, 256 threads, 4x4 micro-tile, K-chunk 8, [kbeg,kend).
// Prefetch next chunk into regs during compute (hides global latency).
// EPI 0: C = elu(acc + X1[col])
// EPI 3: wv update: C=(1-u)*C+u*tanh(X1[(row%200)*200+col]+acc), u=X2;
//        optional fused copy-out to out2 (dtype by *fl) at final-wv offset
// EPI 4: atomicAdd(C, acc)  (K-split P@AW; C pre-init with bias)
template<int EPI, bool AISB, bool BISB>
__device__ void gemm_body(const void* A, int lda, const void* B, int M, int K,
                          int kbeg, int kend,
                          const float* X1, const float* X2, float* C,
                          int row0, int c0, const int* fl, void* out2) {
    const int N = DIM;
    int tid = threadIdx.x;
    int tx = tid & 15, ty = tid >> 4;
    __shared__ float As[8][68];
    __shared__ float Bs[8][64];
    float acc[4][4] = {};
    int ar = tid >> 2;
    int ak = (tid & 3) * 2;
    int bk = tid >> 5;
    int bc = (tid & 31) * 2;
    bool aOK = (row0 + ar < M);
    size_t aBase = (size_t)(row0 + ar) * lda + ak;
    bool bOK0 = (c0 + bc < N), bOK1 = (c0 + bc + 1 < N);
    size_t bBase = (size_t)bk * N + c0 + bc;
    float pa0, pa1, pb0, pb1;
    pa0 = aOK  ? ldv<AISB>(A, aBase + kbeg)     : 0.f;
    pa1 = aOK  ? ldv<AISB>(A, aBase + kbeg + 1) : 0.f;
    pb0 = bOK0 ? ldv<BISB>(B, bBase + (size_t)kbeg * N)     : 0.f;
    pb1 = bOK1 ? ldv<BISB>(B, bBase + (size_t)kbeg * N + 1) : 0.f;
    for (int k0 = kbeg; k0 < kend; k0 += 8) {
        __syncthreads();
        As[ak][ar] = pa0; As[ak + 1][ar] = pa1;
        Bs[bk][bc] = pb0; Bs[bk][bc + 1]  = pb1;
        __syncthreads();
        int kn = k0 + 8;
        if (kn < kend) {
            pa0 = aOK  ? ldv<AISB>(A, aBase + kn)     : 0.f;
            pa1 = aOK  ? ldv<AISB>(A, aBase + kn + 1) : 0.f;
            pb0 = bOK0 ? ldv<BISB>(B, bBase + (size_t)kn * N)     : 0.f;
            pb1 = bOK1 ? ldv<BISB>(B, bBase + (size_t)kn * N + 1) : 0.f;
        }
#pragma unroll
        for (int kk = 0; kk < 8; kk++) {
            float av[4], bv[4];
            *(float4*)av = *(const float4*)&As[kk][ty * 4];
            *(float4*)bv = *(const float4*)&Bs[kk][tx * 4];
#pragma unroll
            for (int i = 0; i < 4; i++)
#pragma unroll
                for (int j = 0; j < 4; j++) acc[i][j] += av[i] * bv[j];
        }
    }
#pragma unroll
    for (int i = 0; i < 4; i++) {
        int row = row0 + ty * 4 + i;
        if (row >= M) continue;
        int a200 = row - (row / 200) * 200;
#pragma unroll
        for (int j = 0; j < 4; j++) {
            int col = c0 + tx * 4 + j;
            if (col >= N) continue;
            float v = acc[i][j];
            size_t ci = (size_t)row * 200 + col;
            if (EPI == 0) {
                C[ci] = eluf(v + X1[col]);
            } else if (EPI == 3) {
                float uu = X2[ci];
                float hc = tanhf(X1[a200 * 200 + col] + v);
                float nv = (1.f - uu) * C[ci] + uu * hc;
                C[ci] = nv;
                if (out2) {
                    size_t oo = (size_t)SEQ * N_NODE * DIM + ci;
                    if (*fl) stv<true>(out2, oo, nv); else stv<false>(out2, oo, nv);
                }
            } else {
                atomicAdd(&C[ci], v);
            }
        }
    }
}

// fused r+u gate GEMM, pipelined: A=wv [1600x200], Br=Ur, Bu=Uu f32.
__global__ __launch_bounds__(256) void k_gemm_e12(const float* A,
        const float* Br, const float* Bu, const float* Gr, const float* Gu,
        float* rw, float* u) {
    const int M = NH * DIM, K = DIM, N = DIM;
    int row0 = blockIdx.y * 64, c0 = blockIdx.x * 64;
    int tid = threadIdx.x;
    int tx = tid & 15, ty = tid >> 4;
    __shared__ float As[8][68];
    __shared__ float Bsr[8][64];
    __shared__ float Bsu[8][64];
    float accR[4][4] = {}, accU[4][4] = {};
    int ar = tid >> 2, ak = (tid & 3) * 2;
    int bk = tid >> 5, bc = (tid & 31) * 2;
    bool aOK = (row0 + ar < M);
    size_t aBase = (size_t)(row0 + ar) * K + ak;
    bool bOK0 = (c0 + bc < N), bOK1 = (c0 + bc + 1 < N);
    size_t bBase = (size_t)bk * N + c0 + bc;
    float pa0, pa1, pr0, pr1, pu0, pu1;
    pa0 = aOK ? A[aBase] : 0.f;
    pa1 = aOK ? A[aBase + 1] : 0.f;
    pr0 = bOK0 ? Br[bBase] : 0.f;  pr1 = bOK1 ? Br[bBase + 1] : 0.f;
    pu0 = bOK0 ? Bu[bBase] : 0.f;  pu1 = bOK1 ? Bu[bBase + 1] : 0.f;
    for (int k0 = 0; k0 < K; k0 += 8) {
        __syncthreads();
        As[ak][ar] = pa0; As[ak + 1][ar] = pa1;
        Bsr[bk][bc] = pr0; Bsr[bk][bc + 1] = pr1;
        Bsu[bk][bc] = pu0; Bsu[bk][bc + 1] = pu1;
        __syncthreads();
        int kn = k0 + 8;
        if (kn < K) {
            pa0 = aOK ? A[aBase + kn] : 0.f;
            pa1 = aOK ? A[aBase + kn + 1] : 0.f;
            pr0 = bOK0 ? Br[bBase + (size_t)kn * N] : 0.f;
            pr1 = bOK1 ? Br[bBase + (size_t)kn * N + 1] : 0.f;
            pu0 = bOK0 ? Bu[bBase + (size_t)kn * N] : 0.f;
            pu1 = bOK1 ? Bu[bBase + (size_t)kn * N + 1] : 0.f;
        }
#pragma unroll
        for (int kk = 0; kk < 8; kk++) {
            float av[4], bvr[4], bvu[4];
            *(float4*)av  = *(const float4*)&As[kk][ty * 4];
            *(float4*)bvr = *(const float4*)&Bsr[kk][tx * 4];
            *(float4*)bvu = *(const float4*)&Bsu[kk][tx * 4];
#pragma unroll
            for (int i = 0; i < 4; i++)
#pragma unroll
                for (int j = 0; j < 4; j++) {
                    accR[i][j] += av[i] * bvr[j];
                    accU[i][j] += av[i] * bvu[j];
                }
        }
    }
#pragma unroll
    for (int i = 0; i < 4; i++) {
        int row = row0 + ty * 4 + i;
        if (row >= M) continue;
        int a200 = row - (row / 200) * 200;
#pragma unroll
        for (int j = 0; j < 4; j++) {
            int col = c0 + tx * 4 + j;
            if (col >= N) continue;
            size_t ci = (size_t)row * 200 + col;
            rw[ci] = sigm(Gr[a200 * 200 + col] + accR[i][j]) * A[ci];
            u[ci]  = sigm(Gu[a200 * 200 + col] + accU[i][j]);
        }
    }
}

__global__ __launch_bounds__(256) void k_gemm_e0(const int* fl, int useIsb,
        const void* A, int lda, const float* B, int M, int K,
        const float* bias, float* C) {
    int row0 = blockIdx.y * 64, c0 = blockIdx.x * 64;
    if (useIsb && *fl)
        gemm_body<0, true , false>(A, lda, B, M, K, 0, K, bias, nullptr, C, row0, c0, nullptr, nullptr);
    else
        gemm_body<0, false, false>(A, lda, B, M, K, 0, K, bias, nullptr, C, row0, c0, nullptr, nullptr);
}
__global__ __launch_bounds__(256) void k_gemm_e3(const float* A, const float* B,
        const float* G0, const float* U, float* WV, const int* fl, void* out2) {
    gemm_body<3, false, false>(A, DIM, B, NH * DIM, DIM, 0, DIM, G0, U, WV,
                               blockIdx.y * 64, blockIdx.x * 64, fl, out2);
}

// K-split P@AW (AW stored bf16): z = sg*8 + split; atomicAdd into G
__global__ __launch_bounds__(256) void k_pggemm(const int* fl,
        const void* P0, const void* P1, const void* P2,
        const bf16* AWb, float* G) {
    int z = blockIdx.z;
    int sg = z >> 3, split = z & 7;
    int g = sg - (sg / 3) * 3;
    const void* A = (g == 0) ? P0 : (g == 1) ? P1 : P2;
    const void* B = AWb + (size_t)sg * N_NODE * DIM;
    float* C = G + (size_t)sg * DIM * DIM;
    int row0 = blockIdx.y * 64, c0 = blockIdx.x * 64;
    int kbeg = split * (N_NODE / 8), kend = kbeg + N_NODE / 8;
    if (*fl) gemm_body<4, true , true>(A, N_NODE, B, DIM, N_NODE, kbeg, kend, nullptr, nullptr, C, row0, c0, nullptr, nullptr);
    else     gemm_body<4, false, true>(A, N_NODE, B, DIM, N_NODE, kbeg, kend, nullptr, nullptr, C, row0, c0, nullptr, nullptr);
}

// ---------------- merged prep ----------------
// sections: [0,80512) W1t/W2t/b1f/b2f; [80512,200512) Utf; [200512,520512) wv;
// [520512,880512) G init from b-inputs; [880512,3338112) Wcat bf16 [4096][608]
template<bool ISB>
__device__ void prep_body(const void* W1, const void* b1, const void* W2, const void* b2,
                          const void* Ur, const void* Uu, const void* Uh,
                          const void* br, const void* bu, const void* bh,
                          const void* iwv, const void* Wr, const void* Wu, const void* Wh,
                          float* W1t, float* W2t, float* b1f, float* b2f,
                          float* Utf, float* wv, float* G, unsigned short* Wcat) {
    int idx = blockIdx.x * 256 + threadIdx.x;
    if (idx < 40000) {
        int k = idx / 200, n = idx % 200;
        W1t[idx] = ldv<ISB>(W1, (size_t)n * 200 + k);
    } else if (idx < 80000) {
        int r = idx - 40000;
        int k = r / 200, n = r % 200;
        float s = 0.f;
        for (int h = 0; h < NH; h++) s += ldv<ISB>(W2, (size_t)n * 1600 + h * 200 + k);
        W2t[r] = s;
    } else if (idx < 80512) {
        int j = idx - 80000;
        if (j < 256)      b1f[j] = (j < 200) ? ldv<ISB>(b1, j) : 0.f;
        else              b2f[j - 256] = (j - 256 < 200) ? ldv<ISB>(b2, j - 256) : 0.f;
    } else if (idx < 200512) {
        int j = idx - 80512;
        int g = j / 40000, r = j - g * 40000;
        const void* U = (g == 0) ? Ur : (g == 1) ? Uu : Uh;
        Utf[j] = ldv<ISB>(U, r);
    } else if (idx < 520512) {
        wv[idx - 200512] = ldv<ISB>(iwv, idx - 200512);
    } else if (idx < 880512) {
        int j = idx - 520512;                 // [0, 360000)
        int sg = j / 40000, r = j - sg * 40000;
        int g = sg - (sg / 3) * 3;
        const void* bb = (g == 0) ? br : (g == 1) ? bu : bh;
        G[j] = ldv<ISB>(bb, r);
    } else {
        int j = idx - 880512;                 // [0, 2457600)
        if (j < 4096 * 600) {
            int k = j / 600, c = j - k * 600;
            int g = (c < 200) ? 0 : (c < 400 ? 1 : 2);
            int o = c - g * 200;
            const void* W = (g == 0) ? Wr : (g == 1) ? Wu : Wh;
            bf16 v = __float2bfloat16(ldv<ISB>(W, (size_t)k * 200 + o));
            Wcat[(size_t)k * 608 + c] = *(unsigned short*)&v;
        }
    }
}
__global__ void k_prep(const int* fl, const void* W1, const void* b1, const void* W2,
                       const void* b2, const void* Ur, const void* Uu, const void* Uh,
                       const void* br, const void* bu, const void* bh, const void* iwv,
                       const void* Wr, const void* Wu, const void* Wh,
                       float* W1t, float* W2t, float* b1f, float* b2f,
                       float* Utf, float* wv, float* G, unsigned short* Wcat) {
    if (*fl) prep_body<true >(W1, b1, W2, b2, Ur, Uu, Uh, br, bu, bh, iwv, Wr, Wu, Wh,
                              W1t, W2t, b1f, b2f, Utf, wv, G, Wcat);
    else     prep_body<false>(W1, b1, W2, b2, Ur, Uu, Uh, br, bu, bh, iwv, Wr, Wu, Wh,
                              W1t, W2t, b1f, b2f, Utf, wv, G, Wcat);
}

// ---------------- softmax (verified round 6) ----------------
template<bool ISB>
__device__ void softmax_body(const float* O, void* out) {
    __shared__ float tile[200 * 65];
    __shared__ float pm[4 * 64];
    __shared__ float ps[4 * 64];
    __shared__ float sm_m[64];
    __shared__ float sm_inv[64];
    int t = blockIdx.y;
    int i0 = blockIdx.x * 64;
    const float* ob = O + (size_t)t * N_NODE * DIM;
    int tid = threadIdx.x;
    for (int idx = tid; idx < 200 * 64; idx += 256) {
        int j = idx >> 6, c = idx & 63;
        tile[j * 65 + c] = ob[(size_t)j * N_NODE + i0 + c];
    }
    __syncthreads();
    int g = tid >> 6, lane = tid & 63;
    int j0 = g * 50, j1 = j0 + 50;
    float mp = -1e30f;
    for (int j = j0; j < j1; j++) mp = fmaxf(mp, tile[j * 65 + lane]);
    pm[g * 64 + lane] = mp;
    __syncthreads();
    if (tid < 64)
        sm_m[tid] = fmaxf(fmaxf(pm[tid], pm[64 + tid]), fmaxf(pm[128 + tid], pm[192 + tid]));
    __syncthreads();
    float mv = sm_m[lane];
    float sp = 0.f;
    for (int j = j0; j < j1; j++) {
        float e = expf(tile[j * 65 + lane] - mv);
        tile[j * 65 + lane] = e;
        sp += e;
    }
    ps[g * 64 + lane] = sp;
    __syncthreads();
    if (tid < 64)
        sm_inv[tid] = 1.f / (ps[tid] + ps[64 + tid] + ps[128 + tid] + ps[192 + tid]);
    __syncthreads();
    size_t ob2 = ((size_t)t * N_NODE + i0) * DIM;
    for (int idx = tid; idx < 64 * 200; idx += 256) {
        int il = idx / 200, j = idx - il * 200;
        stv<ISB>(out, ob2 + (size_t)il * DIM + j, tile[j * 65 + il] * sm_inv[il]);
    }
}
__global__ __launch_bounds__(256) void k_softmax(const int* fl, const float* O, void* out) {
    if (*fl) softmax_body<true>(O, out); else softmax_body<false>(O, out);
}

// ---------------- sparse A@W: whole-row compaction + bf16 Wcat gather ----
// One block per (row i, step s). Compact all ~41 nz in one pass (2 barriers),
// then gather from Wcat[4096][608] bf16 with u32 pair loads, unrolled x4.
// Thread t: pair A = cols (2t, 2t+1); threads t<44: pair B = (512+2t, 513+2t).
// (Gate boundaries 200/400 are even -> pairs never straddle gates.)
template<bool ISB>
__device__ void aw_body(const void* adjs, const unsigned short* Wcat, bf16* AWb) {
    int i = blockIdx.x;
    int s = blockIdx.y;
    size_t arow = ((size_t)(s + 1) * N_NODE + i) * N_NODE;
    __shared__ int   s_k[512];
    __shared__ float s_v[512];
    __shared__ int   s_cnt;
    int tid = threadIdx.x;
    if (tid == 0) s_cnt = 0;
    __syncthreads();
    float vals[16];
#pragma unroll
    for (int c = 0; c < 4; c++) {
        int col = c * 1024 + tid * 4;
        if (ISB) {
            ushort4 u = *(const ushort4*)((const unsigned short*)adjs + arow + col);
            vals[c*4+0] = __uint_as_float((unsigned)u.x << 16);
            vals[c*4+1] = __uint_as_float((unsigned)u.y << 16);
            vals[c*4+2] = __uint_as_float((unsigned)u.z << 16);
            vals[c*4+3] = __uint_as_float((unsigned)u.w << 16);
        } else {
            float4 f = *(const float4*)((const float*)adjs + arow + col);
            vals[c*4+0] = f.x; vals[c*4+1] = f.y; vals[c*4+2] = f.z; vals[c*4+3] = f.w;
        }
    }
#pragma unroll
    for (int q = 0; q < 16; q++) {
        if (vals[q] != 0.f) {
            int p = atomicAdd(&s_cnt, 1);
            if (p < 512) { s_k[p] = (q >> 2) * 1024 + tid * 4 + (q & 3); s_v[p] = vals[q]; }
        }
    }
    __syncthreads();
    int n = s_cnt < 512 ? s_cnt : 512;
    float a0 = 0.f, a1 = 0.f, d0 = 0.f, d1 = 0.f;
    bool hasB = (tid < 44);
    int offA = 2 * tid, offB = 512 + 2 * tid;
    int e = 0;
    for (; e + 4 <= n; e += 4) {
        int   k0 = s_k[e],   k1 = s_k[e+1], k2 = s_k[e+2], k3 = s_k[e+3];
        float v0 = s_v[e],   v1 = s_v[e+1], v2 = s_v[e+2], v3 = s_v[e+3];
        unsigned wa0 = *(const unsigned*)(Wcat + (size_t)k0 * 608 + offA);
        unsigned wa1 = *(const unsigned*)(Wcat + (size_t)k1 * 608 + offA);
        unsigned wa2 = *(const unsigned*)(Wcat + (size_t)k2 * 608 + offA);
        unsigned wa3 = *(const unsigned*)(Wcat + (size_t)k3 * 608 + offA);
        if (hasB) {
            unsigned wb0 = *(const unsigned*)(Wcat + (size_t)k0 * 608 + offB);
            unsigned wb1 = *(const unsigned*)(Wcat + (size_t)k1 * 608 + offB);
            unsigned wb2 = *(const unsigned*)(Wcat + (size_t)k2 * 608 + offB);
            unsigned wb3 = *(const unsigned*)(Wcat + (size_t)k3 * 608 + offB);
            d0 += v0*bflo(wb0) + v1*bflo(wb1) + v2*bflo(wb2) + v3*bflo(wb3);
            d1 += v0*bfhi(wb0) + v1*bfhi(wb1) + v2*bfhi(wb2) + v3*bfhi(wb3);
        }
        a0 += v0*bflo(wa0) + v1*bflo(wa1) + v2*bflo(wa2) + v3*bflo(wa3);
        a1 += v0*bfhi(wa0) + v1*bfhi(wa1) + v2*bfhi(wa2) + v3*bfhi(wa3);
    }
    for (; e < n; e++) {
        int k = s_k[e]; float v = s_v[e];
        unsigned wa = *(const unsigned*)(Wcat + (size_t)k * 608 + offA);
        a0 += v * bflo(wa); a1 += v * bfhi(wa);
        if (hasB) {
            unsigned wb = *(const unsigned*)(Wcat + (size_t)k * 608 + offB);
            d0 += v * bflo(wb); d1 += v * bfhi(wb);
        }
    }
    int gA = (offA < 200) ? 0 : (offA < 400 ? 1 : 2);
    int oA = offA - gA * 200;
    size_t wbase = ((size_t)(s * 3 + gA) * N_NODE + i) * DIM + oA;
    AWb[wbase]     = __float2bfloat16(a0);
    AWb[wbase + 1] = __float2bfloat16(a1);
    if (hasB) {
        int oB = offB - 400;
        size_t wb2 = ((size_t)(s * 3 + 2) * N_NODE + i) * DIM + oB;
        AWb[wb2]     = __float2bfloat16(d0);
        AWb[wb2 + 1] = __float2bfloat16(d1);
    }
}
__global__ __launch_bounds__(256) void k_aw(const int* fl, const void* adjs,
        const unsigned short* Wcat, bf16* AWb) {
    if (*fl) aw_body<true>(adjs, Wcat, AWb);
    else     aw_body<false>(adjs, Wcat, AWb);
}

extern "C" void kernel_launch(void* const* d_in, const int* in_sizes, int n_in,
                              void* d_out, int out_size, void* d_ws, size_t ws_size,
                              hipStream_t stream) {
    const void* adjs    = d_in[0];
    const void* feats   = d_in[1];
    const void* init_wv = d_in[3];
    const void* W1 = d_in[4];
    const void* b1 = d_in[5];
    const void* W2 = d_in[10];
    const void* b2 = d_in[11];
    const void* Wr = d_in[16];
    const void* Ur = d_in[17];
    const void* Pr = d_in[18];
    const void* br = d_in[19];
    const void* Wu = d_in[20];
    const void* Uu = d_in[21];
    const void* Pu = d_in[22];
    const void* bu = d_in[23];
    const void* Wh = d_in[24];
    const void* Uh = d_in[25];
    const void* Ph = d_in[26];
    const void* bh = d_in[27];

    // ---- workspace (floats), phase overlay ----
    // OV [64, 6,553,664): phase A = Wcat (1,245,184 f) + AWb (3,686,400 f);
    //                     phase B = Hbuf (3,276,800) + Obuf (3,276,800)
    int*   flag = (int*)d_ws;
    float* base = (float*)d_ws;
    unsigned short* Wcat = (unsigned short*)(base + 64);        // 4096x608 bf16
    bf16*  AWb  = (bf16*)(base + 64 + 1245184);                 // 9x4096x200 bf16
    float* Hbuf = base + 64;
    float* Obuf = Hbuf + 3276800;
    float* W1t  = base + 6553664;         // 40,000
    float* W2t  = W1t + 40000;            // 40,000
    float* b1f  = W2t + 40000;            // 256
    float* b2f  = b1f + 256;              // 256
    float* ubuf = b2f + 256;              // 320,000
    float* rwbuf= ubuf + 320000;          // 320,000
    float* Utf  = rwbuf + 320000;         // 120,000
    float* G    = Utf + 120000;           // 360,000
    float* wv   = G + 360000;             // 320,000
    // end 8,074,176 floats = 30.8 MB

    const int M = SEQ * N_NODE;           // 16384

    k_detect<<<1, 256, 0, stream>>>(feats, flag);
    k_prep<<<(3338112 + 255) / 256, 256, 0, stream>>>(
        flag, W1, b1, W2, b2, Ur, Uu, Uh, br, bu, bh, init_wv, Wr, Wu, Wh,
        W1t, W2t, b1f, b2f, Utf, wv, G, Wcat);

    // ---- GRU front half: sparse A@W, then P@AW (uses OV phase A) ----
    {
        dim3 g(N_NODE, 3);
        k_aw<<<g, 256, 0, stream>>>(flag, adjs, Wcat, AWb);
    }
    {
        dim3 g(4, 4, 72);
        k_pggemm<<<g, 256, 0, stream>>>(flag, Pr, Pu, Ph, AWb, G);
    }

    // ---- GAT branch (reuses OV as phase B) ----
    {
        dim3 g(4, M / 64);
        k_gemm_e0<<<g, 256, 0, stream>>>(flag, 1, feats, DIM, W1t, M, DIM, b1f, Hbuf);
        k_gemm_e0<<<g, 256, 0, stream>>>(flag, 0, Hbuf, DIM, W2t, M, DIM, b2f, Obuf);
    }
    {
        dim3 g(N_NODE / 64, SEQ);
        k_softmax<<<g, 256, 0, stream>>>(flag, Obuf, d_out);
    }

    // ---- GRU chain ----
    {
        dim3 g(4, NH * DIM / 64);   // (4, 25)
        for (int s = 0; s < 3; s++) {
            const float* Gr = G + (size_t)(s * 3 + 0) * DIM * DIM;
            const float* Gu = G + (size_t)(s * 3 + 1) * DIM * DIM;
            const float* Gh = G + (size_t)(s * 3 + 2) * DIM * DIM;
            void* out2 = (s == 2) ? d_out : nullptr;
            k_gemm_e12<<<g, 256, 0, stream>>>(wv, Utf + 0, Utf + 40000, Gr, Gu, rwbuf, ubuf);
            k_gemm_e3<<<g, 256, 0, stream>>>(rwbuf, Utf + 80000, Gh, ubuf, wv, flag, out2);
        }
    }
}

// Round 8
// 668.559 us; speedup vs baseline: 2.8239x; 1.1858x over previous
//
#include <hip/hip_runtime.h>
#include <hip/hip_bf16.h>
#include <math.h>

typedef __hip_bfloat16 bf16;
typedef __attribute__((ext_vector_type(8))) short short8;
typedef __attribute__((ext_vector_type(4))) float f32x4;

#define N_NODE 4096
#define DIM 200
#define NH 8
#define SEQ 4
#define TLDA 40   // LDS tile row stride in shorts (80 B: 16B-aligned frags, 2-way banks)

__device__ __forceinline__ float eluf(float x) { return x > 0.f ? x : expm1f(x); }
__device__ __forceinline__ float sigm(float x) { return 1.f / (1.f + expf(-x)); }

template<bool ISB>
__device__ __forceinline__ float ldv(const void* p, size_t i) {
    if (ISB) return __bfloat162float(((const bf16*)p)[i]);
    else     return ((const float*)p)[i];
}
template<bool ISB>
__device__ __forceinline__ void stv(void* p, size_t i, float v) {
    if (ISB) ((bf16*)p)[i] = __float2bfloat16(v);
    else     ((float*)p)[i] = v;
}
__device__ __forceinline__ float bflo(unsigned u) { return __uint_as_float((u & 0xffffu) << 16); }
__device__ __forceinline__ float bfhi(unsigned u) { return __uint_as_float(u & 0xffff0000u); }
__device__ __forceinline__ short f2bs(float v) {
    bf16 h = __float2bfloat16(v);
    return *(short*)&h;
}

// Detect input dtype from feats (values ~ N(0,1)). See round-1/2 analysis.
__global__ void k_detect(const void* feats, int* flag) {
    __shared__ int cnt;
    if (threadIdx.x == 0) cnt = 0;
    __syncthreads();
    const unsigned short* u = (const unsigned short*)feats;
    unsigned short v = u[2 * threadIdx.x];
    int e = (v >> 7) & 0xFF;
    if (e >= 100 && e <= 140) atomicAdd(&cnt, 1);
    __syncthreads();
    if (threadIdx.x == 0) *flag = (cnt >= 128) ? 1 : 0;
}

// ---------------- MFMA GEMM core ----------------
// Block = 256 thr = 4 waves. C-tile 64x64; wave w -> cols [w*16,w*16+16),
// rows 0..63 (4 row-frags). K-chunk 32 staged to LDS bf16, k-contiguous:
// As[row][k] / Bs[col][k], stride TLDA. Fragments (HW-verified gfx950):
// A: m=lane&15, k=quad*8+j; B: n=lane&15, k=quad*8+j; D: col=lane&15,
// row=quad*4+reg. Reg-prefetch pipeline (round-7 proven pattern).
// EPI 0: C=elu(acc+X1[col]); EPI 3: GRU wv update (+opt fused out2 copy);
// EPI 4: atomicAdd(C, acc) (K-split, C pre-init with bias).

template<bool AISB>
__device__ __forceinline__ void ldA8(const void* A, int lda, int arow, bool rowOK,
                                     int kk, int K, float* la) {
    if (rowOK && kk + 8 <= K) {
        if (AISB) {
            const unsigned short* ap = (const unsigned short*)A + (size_t)arow * lda + kk;
            uint4 u = *(const uint4*)ap;
            la[0] = bflo(u.x); la[1] = bfhi(u.x);
            la[2] = bflo(u.y); la[3] = bfhi(u.y);
            la[4] = bflo(u.z); la[5] = bfhi(u.z);
            la[6] = bflo(u.w); la[7] = bfhi(u.w);
        } else {
            const float* ap = (const float*)A + (size_t)arow * lda + kk;
            float4 f0 = *(const float4*)ap;
            float4 f1 = *(const float4*)(ap + 4);
            la[0] = f0.x; la[1] = f0.y; la[2] = f0.z; la[3] = f0.w;
            la[4] = f1.x; la[5] = f1.y; la[6] = f1.z; la[7] = f1.w;
        }
    } else {
#pragma unroll
        for (int j = 0; j < 8; j++)
            la[j] = (rowOK && kk + j < K) ? ldv<AISB>(A, (size_t)arow * lda + kk + j) : 0.f;
    }
}
template<bool BISB>
__device__ __forceinline__ void ldB8(const void* B, int gcol, bool colOK,
                                     int kk, int K, float* lb) {
#pragma unroll
    for (int j = 0; j < 8; j++)
        lb[j] = (colOK && kk + j < K) ? ldv<BISB>(B, (size_t)(kk + j) * DIM + gcol) : 0.f;
}

template<int EPI, bool AISB, bool BISB>
__device__ void mgemm(const void* A, int lda, const void* B, int M, int K,
                      int kbeg, int kend, const float* X1, const float* X2,
                      float* C, int row0, int c0, const int* fl, void* out2) {
    const int N = DIM;
    int tid = threadIdx.x;
    int wave = tid >> 6, lane = tid & 63;
    int m16 = lane & 15, q = lane >> 4;
    __shared__ short As[64 * TLDA];
    __shared__ short Bs[64 * TLDA];
    int s_row = tid >> 2;
    int s_k   = (tid & 3) * 8;
    int b_col = tid & 63;
    int b_kg  = (tid >> 6) * 8;
    int arow = row0 + s_row;
    bool rowOK = arow < M;
    int gcol = c0 + b_col;
    bool colOK = gcol < N;
    float la[8], lb[8];
    ldA8<AISB>(A, lda, arow, rowOK, kbeg + s_k, K, la);
    ldB8<BISB>(B, gcol, colOK, kbeg + b_kg, K, lb);
    f32x4 acc[4] = {};
    for (int k0 = kbeg; k0 < kend; k0 += 32) {
        __syncthreads();
        short8 a8, b8;
#pragma unroll
        for (int j = 0; j < 8; j++) { a8[j] = f2bs(la[j]); b8[j] = f2bs(lb[j]); }
        *(short8*)&As[s_row * TLDA + s_k] = a8;
        *(short8*)&Bs[b_col * TLDA + b_kg] = b8;
        __syncthreads();
        int kn = k0 + 32;
        if (kn < kend) {
            ldA8<AISB>(A, lda, arow, rowOK, kn + s_k, K, la);
            ldB8<BISB>(B, gcol, colOK, kn + b_kg, K, lb);
        }
        short8 bf = *(short8*)&Bs[(wave * 16 + m16) * TLDA + q * 8];
#pragma unroll
        for (int r = 0; r < 4; r++) {
            short8 af = *(short8*)&As[(r * 16 + m16) * TLDA + q * 8];
            acc[r] = __builtin_amdgcn_mfma_f32_16x16x32_bf16(af, bf, acc[r], 0, 0, 0);
        }
    }
    int colw = c0 + wave * 16 + m16;
    if (colw >= N) return;
#pragma unroll
    for (int r = 0; r < 4; r++) {
        int rowb = row0 + r * 16 + q * 4;
#pragma unroll
        for (int reg = 0; reg < 4; reg++) {
            int row = rowb + reg;
            if (row >= M) continue;
            float v = acc[r][reg];
            size_t ci = (size_t)row * 200 + colw;
            if (EPI == 0) {
                C[ci] = eluf(v + X1[colw]);
            } else if (EPI == 3) {
                int a200 = row - (row / 200) * 200;
                float uu = X2[ci];
                float hc = tanhf(X1[a200 * 200 + colw] + v);
                float nv = (1.f - uu) * C[ci] + uu * hc;
                C[ci] = nv;
                if (out2) {
                    size_t oo = (size_t)SEQ * N_NODE * DIM + ci;
                    if (*fl) stv<true>(out2, oo, nv); else stv<false>(out2, oo, nv);
                }
            } else {
                atomicAdd(&C[ci], v);
            }
        }
    }
}

// dual-B (r+u gate) MFMA GEMM: A=wv [1600x200] f32, Br=Ur, Bu=Uu f32.
__global__ __launch_bounds__(256) void k_gemm_e12(const float* A,
        const float* Br, const float* Bu, const float* Gr, const float* Gu,
        float* rw, float* u) {
    const int M = NH * DIM, K = DIM, N = DIM;
    int row0 = blockIdx.y * 64, c0 = blockIdx.x * 64;
    int tid = threadIdx.x;
    int wave = tid >> 6, lane = tid & 63;
    int m16 = lane & 15, q = lane >> 4;
    __shared__ short As[64 * TLDA];
    __shared__ short Bsr[64 * TLDA];
    __shared__ short Bsu[64 * TLDA];
    int s_row = tid >> 2;
    int s_k   = (tid & 3) * 8;
    int b_col = tid & 63;
    int b_kg  = (tid >> 6) * 8;
    int arow = row0 + s_row;
    bool rowOK = arow < M;
    int gcol = c0 + b_col;
    bool colOK = gcol < N;
    float la[8], lbr[8], lbu[8];
    ldA8<false>(A, K, arow, rowOK, s_k, K, la);
    ldB8<false>(Br, gcol, colOK, b_kg, K, lbr);
    ldB8<false>(Bu, gcol, colOK, b_kg, K, lbu);
    f32x4 accR[4] = {}, accU[4] = {};
    for (int k0 = 0; k0 < K; k0 += 32) {
        __syncthreads();
        short8 a8, r8, u8;
#pragma unroll
        for (int j = 0; j < 8; j++) {
            a8[j] = f2bs(la[j]); r8[j] = f2bs(lbr[j]); u8[j] = f2bs(lbu[j]);
        }
        *(short8*)&As[s_row * TLDA + s_k] = a8;
        *(short8*)&Bsr[b_col * TLDA + b_kg] = r8;
        *(short8*)&Bsu[b_col * TLDA + b_kg] = u8;
        __syncthreads();
        int kn = k0 + 32;
        if (kn < K) {
            ldA8<false>(A, K, arow, rowOK, kn + s_k, K, la);
            ldB8<false>(Br, gcol, colOK, kn + b_kg, K, lbr);
            ldB8<false>(Bu, gcol, colOK, kn + b_kg, K, lbu);
        }
        short8 bfr = *(short8*)&Bsr[(wave * 16 + m16) * TLDA + q * 8];
        short8 bfu = *(short8*)&Bsu[(wave * 16 + m16) * TLDA + q * 8];
#pragma unroll
        for (int r = 0; r < 4; r++) {
            short8 af = *(short8*)&As[(r * 16 + m16) * TLDA + q * 8];
            accR[r] = __builtin_amdgcn_mfma_f32_16x16x32_bf16(af, bfr, accR[r], 0, 0, 0);
            accU[r] = __builtin_amdgcn_mfma_f32_16x16x32_bf16(af, bfu, accU[r], 0, 0, 0);
        }
    }
    int colw = c0 + wave * 16 + m16;
    if (colw >= N) return;
#pragma unroll
    for (int r = 0; r < 4; r++) {
        int rowb = row0 + r * 16 + q * 4;
#pragma unroll
        for (int reg = 0; reg < 4; reg++) {
            int row = rowb + reg;
            if (row >= M) continue;
            int a200 = row - (row / 200) * 200;
            size_t ci = (size_t)row * 200 + colw;
            rw[ci] = sigm(Gr[a200 * 200 + colw] + accR[r][reg]) * A[ci];
            u[ci]  = sigm(Gu[a200 * 200 + colw] + accU[r][reg]);
        }
    }
}

__global__ __launch_bounds__(256) void k_gemm_e0(const int* fl, int useIsb,
        const void* A, int lda, const float* B, int M, int K,
        const float* bias, float* C) {
    int row0 = blockIdx.y * 64, c0 = blockIdx.x * 64;
    if (useIsb && *fl)
        mgemm<0, true , false>(A, lda, B, M, K, 0, K, bias, nullptr, C, row0, c0, nullptr, nullptr);
    else
        mgemm<0, false, false>(A, lda, B, M, K, 0, K, bias, nullptr, C, row0, c0, nullptr, nullptr);
}
__global__ __launch_bounds__(256) void k_gemm_e3(const float* A, const float* B,
        const float* G0, const float* U, float* WV, const int* fl, void* out2) {
    mgemm<3, false, false>(A, DIM, B, NH * DIM, DIM, 0, DIM, G0, U, WV,
                           blockIdx.y * 64, blockIdx.x * 64, fl, out2);
}
// K-split P@AW (AW bf16): z = sg*8 + split; atomicAdd into bias-init G
__global__ __launch_bounds__(256) void k_pggemm(const int* fl,
        const void* P0, const void* P1, const void* P2,
        const bf16* AWb, float* G) {
    int z = blockIdx.z;
    int sg = z >> 3, split = z & 7;
    int g = sg - (sg / 3) * 3;
    const void* A = (g == 0) ? P0 : (g == 1) ? P1 : P2;
    const void* B = AWb + (size_t)sg * N_NODE * DIM;
    float* C = G + (size_t)sg * DIM * DIM;
    int row0 = blockIdx.y * 64, c0 = blockIdx.x * 64;
    int kbeg = split * (N_NODE / 8), kend = kbeg + N_NODE / 8;
    if (*fl) mgemm<4, true , true>(A, N_NODE, B, DIM, N_NODE, kbeg, kend, nullptr, nullptr, C, row0, c0, nullptr, nullptr);
    else     mgemm<4, false, true>(A, N_NODE, B, DIM, N_NODE, kbeg, kend, nullptr, nullptr, C, row0, c0, nullptr, nullptr);
}

// ---------------- merged prep (verified round 7) ----------------
template<bool ISB>
__device__ void prep_body(const void* W1, const void* b1, const void* W2, const void* b2,
                          const void* Ur, const void* Uu, const void* Uh,
                          const void* br, const void* bu, const void* bh,
                          const void* iwv, const void* Wr, const void* Wu, const void* Wh,
                          float* W1t, float* W2t, float* b1f, float* b2f,
                          float* Utf, float* wv, float* G, unsigned short* Wcat) {
    int idx = blockIdx.x * 256 + threadIdx.x;
    if (idx < 40000) {
        int k = idx / 200, n = idx % 200;
        W1t[idx] = ldv<ISB>(W1, (size_t)n * 200 + k);
    } else if (idx < 80000) {
        int r = idx - 40000;
        int k = r / 200, n = r % 200;
        float s = 0.f;
        for (int h = 0; h < NH; h++) s += ldv<ISB>(W2, (size_t)n * 1600 + h * 200 + k);
        W2t[r] = s;
    } else if (idx < 80512) {
        int j = idx - 80000;
        if (j < 256)      b1f[j] = (j < 200) ? ldv<ISB>(b1, j) : 0.f;
        else              b2f[j - 256] = (j - 256 < 200) ? ldv<ISB>(b2, j - 256) : 0.f;
    } else if (idx < 200512) {
        int j = idx - 80512;
        int g = j / 40000, r = j - g * 40000;
        const void* U = (g == 0) ? Ur : (g == 1) ? Uu : Uh;
        Utf[j] = ldv<ISB>(U, r);
    } else if (idx < 520512) {
        wv[idx - 200512] = ldv<ISB>(iwv, idx - 200512);
    } else if (idx < 880512) {
        int j = idx - 520512;
        int sg = j / 40000, r = j - sg * 40000;
        int g = sg - (sg / 3) * 3;
        const void* bb = (g == 0) ? br : (g == 1) ? bu : bh;
        G[j] = ldv<ISB>(bb, r);
    } else {
        int j = idx - 880512;
        if (j < 4096 * 600) {
            int k = j / 600, c = j - k * 600;
            int g = (c < 200) ? 0 : (c < 400 ? 1 : 2);
            int o = c - g * 200;
            const void* W = (g == 0) ? Wr : (g == 1) ? Wu : Wh;
            bf16 v = __float2bfloat16(ldv<ISB>(W, (size_t)k * 200 + o));
            Wcat[(size_t)k * 608 + c] = *(unsigned short*)&v;
        }
    }
}
__global__ void k_prep(const int* fl, const void* W1, const void* b1, const void* W2,
                       const void* b2, const void* Ur, const void* Uu, const void* Uh,
                       const void* br, const void* bu, const void* bh, const void* iwv,
                       const void* Wr, const void* Wu, const void* Wh,
                       float* W1t, float* W2t, float* b1f, float* b2f,
                       float* Utf, float* wv, float* G, unsigned short* Wcat) {
    if (*fl) prep_body<true >(W1, b1, W2, b2, Ur, Uu, Uh, br, bu, bh, iwv, Wr, Wu, Wh,
                              W1t, W2t, b1f, b2f, Utf, wv, G, Wcat);
    else     prep_body<false>(W1, b1, W2, b2, Ur, Uu, Uh, br, bu, bh, iwv, Wr, Wu, Wh,
                              W1t, W2t, b1f, b2f, Utf, wv, G, Wcat);
}

// ---------------- softmax (verified round 6) ----------------
template<bool ISB>
__device__ void softmax_body(const float* O, void* out) {
    __shared__ float tile[200 * 65];
    __shared__ float pm[4 * 64];
    __shared__ float ps[4 * 64];
    __shared__ float sm_m[64];
    __shared__ float sm_inv[64];
    int t = blockIdx.y;
    int i0 = blockIdx.x * 64;
    const float* ob = O + (size_t)t * N_NODE * DIM;
    int tid = threadIdx.x;
    for (int idx = tid; idx < 200 * 64; idx += 256) {
        int j = idx >> 6, c = idx & 63;
        tile[j * 65 + c] = ob[(size_t)j * N_NODE + i0 + c];
    }
    __syncthreads();
    int g = tid >> 6, lane = tid & 63;
    int j0 = g * 50, j1 = j0 + 50;
    float mp = -1e30f;
    for (int j = j0; j < j1; j++) mp = fmaxf(mp, tile[j * 65 + lane]);
    pm[g * 64 + lane] = mp;
    __syncthreads();
    if (tid < 64)
        sm_m[tid] = fmaxf(fmaxf(pm[tid], pm[64 + tid]), fmaxf(pm[128 + tid], pm[192 + tid]));
    __syncthreads();
    float mv = sm_m[lane];
    float sp = 0.f;
    for (int j = j0; j < j1; j++) {
        float e = expf(tile[j * 65 + lane] - mv);
        tile[j * 65 + lane] = e;
        sp += e;
    }
    ps[g * 64 + lane] = sp;
    __syncthreads();
    if (tid < 64)
        sm_inv[tid] = 1.f / (ps[tid] + ps[64 + tid] + ps[128 + tid] + ps[192 + tid]);
    __syncthreads();
    size_t ob2 = ((size_t)t * N_NODE + i0) * DIM;
    for (int idx = tid; idx < 64 * 200; idx += 256) {
        int il = idx / 200, j = idx - il * 200;
        stv<ISB>(out, ob2 + (size_t)il * DIM + j, tile[j * 65 + il] * sm_inv[il]);
    }
}
__global__ __launch_bounds__(256) void k_softmax(const int* fl, const float* O, void* out) {
    if (*fl) softmax_body<true>(O, out); else softmax_body<false>(O, out);
}

// ---------------- sparse A@W (verified round 7) ----------------
template<bool ISB>
__device__ void aw_body(const void* adjs, const unsigned short* Wcat, bf16* AWb) {
    int i = blockIdx.x;
    int s = blockIdx.y;
    size_t arow = ((size_t)(s + 1) * N_NODE + i) * N_NODE;
    __shared__ int   s_k[512];
    __shared__ float s_v[512];
    __shared__ int   s_cnt;
    int tid = threadIdx.x;
    if (tid == 0) s_cnt = 0;
    __syncthreads();
    float vals[16];
#pragma unroll
    for (int c = 0; c < 4; c++) {
        int col = c * 1024 + tid * 4;
        if (ISB) {
            ushort4 u = *(const ushort4*)((const unsigned short*)adjs + arow + col);
            vals[c*4+0] = __uint_as_float((unsigned)u.x << 16);
            vals[c*4+1] = __uint_as_float((unsigned)u.y << 16);
            vals[c*4+2] = __uint_as_float((unsigned)u.z << 16);
            vals[c*4+3] = __uint_as_float((unsigned)u.w << 16);
        } else {
            float4 f = *(const float4*)((const float*)adjs + arow + col);
            vals[c*4+0] = f.x; vals[c*4+1] = f.y; vals[c*4+2] = f.z; vals[c*4+3] = f.w;
        }
    }
#pragma unroll
    for (int q = 0; q < 16; q++) {
        if (vals[q] != 0.f) {
            int p = atomicAdd(&s_cnt, 1);
            if (p < 512) { s_k[p] = (q >> 2) * 1024 + tid * 4 + (q & 3); s_v[p] = vals[q]; }
        }
    }
    __syncthreads();
    int n = s_cnt < 512 ? s_cnt : 512;
    float a0 = 0.f, a1 = 0.f, d0 = 0.f, d1 = 0.f;
    bool hasB = (tid < 44);
    int offA = 2 * tid, offB = 512 + 2 * tid;
    int e = 0;
    for (; e + 4 <= n; e += 4) {
        int   k0 = s_k[e],   k1 = s_k[e+1], k2 = s_k[e+2], k3 = s_k[e+3];
        float v0 = s_v[e],   v1 = s_v[e+1], v2 = s_v[e+2], v3 = s_v[e+3];
        unsigned wa0 = *(const unsigned*)(Wcat + (size_t)k0 * 608 + offA);
        unsigned wa1 = *(const unsigned*)(Wcat + (size_t)k1 * 608 + offA);
        unsigned wa2 = *(const unsigned*)(Wcat + (size_t)k2 * 608 + offA);
        unsigned wa3 = *(const unsigned*)(Wcat + (size_t)k3 * 608 + offA);
        if (hasB) {
            unsigned wb0 = *(const unsigned*)(Wcat + (size_t)k0 * 608 + offB);
            unsigned wb1 = *(const unsigned*)(Wcat + (size_t)k1 * 608 + offB);
            unsigned wb2 = *(const unsigned*)(Wcat + (size_t)k2 * 608 + offB);
            unsigned wb3 = *(const unsigned*)(Wcat + (size_t)k3 * 608 + offB);
            d0 += v0*bflo(wb0) + v1*bflo(wb1) + v2*bflo(wb2) + v3*bflo(wb3);
            d1 += v0*bfhi(wb0) + v1*bfhi(wb1) + v2*bfhi(wb2) + v3*bfhi(wb3);
        }
        a0 += v0*bflo(wa0) + v1*bflo(wa1) + v2*bflo(wa2) + v3*bflo(wa3);
        a1 += v0*bfhi(wa0) + v1*bfhi(wa1) + v2*bfhi(wa2) + v3*bfhi(wa3);
    }
    for (; e < n; e++) {
        int k = s_k[e]; float v = s_v[e];
        unsigned wa = *(const unsigned*)(Wcat + (size_t)k * 608 + offA);
        a0 += v * bflo(wa); a1 += v * bfhi(wa);
        if (hasB) {
            unsigned wb = *(const unsigned*)(Wcat + (size_t)k * 608 + offB);
            d0 += v * bflo(wb); d1 += v * bfhi(wb);
        }
    }
    int gA = (offA < 200) ? 0 : (offA < 400 ? 1 : 2);
    int oA = offA - gA * 200;
    size_t wbase = ((size_t)(s * 3 + gA) * N_NODE + i) * DIM + oA;
    AWb[wbase]     = __float2bfloat16(a0);
    AWb[wbase + 1] = __float2bfloat16(a1);
    if (hasB) {
        int oB = offB - 400;
        size_t wb2 = ((size_t)(s * 3 + 2) * N_NODE + i) * DIM + oB;
        AWb[wb2]     = __float2bfloat16(d0);
        AWb[wb2 + 1] = __float2bfloat16(d1);
    }
}
__global__ __launch_bounds__(256) void k_aw(const int* fl, const void* adjs,
        const unsigned short* Wcat, bf16* AWb) {
    if (*fl) aw_body<true>(adjs, Wcat, AWb);
    else     aw_body<false>(adjs, Wcat, AWb);
}

extern "C" void kernel_launch(void* const* d_in, const int* in_sizes, int n_in,
                              void* d_out, int out_size, void* d_ws, size_t ws_size,
                              hipStream_t stream) {
    const void* adjs    = d_in[0];
    const void* feats   = d_in[1];
    const void* init_wv = d_in[3];
    const void* W1 = d_in[4];
    const void* b1 = d_in[5];
    const void* W2 = d_in[10];
    const void* b2 = d_in[11];
    const void* Wr = d_in[16];
    const void* Ur = d_in[17];
    const void* Pr = d_in[18];
    const void* br = d_in[19];
    const void* Wu = d_in[20];
    const void* Uu = d_in[21];
    const void* Pu = d_in[22];
    const void* bu = d_in[23];
    const void* Wh = d_in[24];
    const void* Uh = d_in[25];
    const void* Ph = d_in[26];
    const void* bh = d_in[27];

    // ---- workspace (floats), phase overlay (round-7 layout) ----
    int*   flag = (int*)d_ws;
    float* base = (float*)d_ws;
    unsigned short* Wcat = (unsigned short*)(base + 64);        // 4096x608 bf16
    bf16*  AWb  = (bf16*)(base + 64 + 1245184);                 // 9x4096x200 bf16
    float* Hbuf = base + 64;
    float* Obuf = Hbuf + 3276800;
    float* W1t  = base + 6553664;
    float* W2t  = W1t + 40000;
    float* b1f  = W2t + 40000;
    float* b2f  = b1f + 256;
    float* ubuf = b2f + 256;
    float* rwbuf= ubuf + 320000;
    float* Utf  = rwbuf + 320000;
    float* G    = Utf + 120000;
    float* wv   = G + 360000;

    const int M = SEQ * N_NODE;           // 16384

    k_detect<<<1, 256, 0, stream>>>(feats, flag);
    k_prep<<<(3338112 + 255) / 256, 256, 0, stream>>>(
        flag, W1, b1, W2, b2, Ur, Uu, Uh, br, bu, bh, init_wv, Wr, Wu, Wh,
        W1t, W2t, b1f, b2f, Utf, wv, G, Wcat);

    // ---- GRU front half (overlay phase A) ----
    {
        dim3 g(N_NODE, 3);
        k_aw<<<g, 256, 0, stream>>>(flag, adjs, Wcat, AWb);
    }
    {
        dim3 g(4, 4, 72);
        k_pggemm<<<g, 256, 0, stream>>>(flag, Pr, Pu, Ph, AWb, G);
    }

    // ---- GAT branch (overlay phase B) ----
    {
        dim3 g(4, M / 64);
        k_gemm_e0<<<g, 256, 0, stream>>>(flag, 1, feats, DIM, W1t, M, DIM, b1f, Hbuf);
        k_gemm_e0<<<g, 256, 0, stream>>>(flag, 0, Hbuf, DIM, W2t, M, DIM, b2f, Obuf);
    }
    {
        dim3 g(N_NODE / 64, SEQ);
        k_softmax<<<g, 256, 0, stream>>>(flag, Obuf, d_out);
    }

    // ---- GRU chain ----
    {
        dim3 g(4, NH * DIM / 64);   // (4, 25)
        for (int s = 0; s < 3; s++) {
            const float* Gr = G + (size_t)(s * 3 + 0) * DIM * DIM;
            const float* Gu = G + (size_t)(s * 3 + 1) * DIM * DIM;
            const float* Gh = G + (size_t)(s * 3 + 2) * DIM * DIM;
            void* out2 = (s == 2) ? d_out : nullptr;
            k_gemm_e12<<<g, 256, 0, stream>>>(wv, Utf + 0, Utf + 40000, Gr, Gu, rwbuf, ubuf);
            k_gemm_e3<<<g, 256, 0, stream>>>(rwbuf, Utf + 80000, Gh, ubuf, wv, flag, out2);
        }
    }
}